// Round 14
// baseline (591.277 us; speedup 1.0000x reference)
//
#include <hip/hip_runtime.h>
#include <math.h>
#include <float.h>

#define XG 192
#define YG 132
#define HW 25344           // 192*132
#define NCLS 6
#define NPROP 500
#define LWIN 441
#define CAP 2048           // candidate cap for top-k sort (one-level select)

typedef unsigned short ushort_t;
typedef __attribute__((ext_vector_type(8))) short bf8v;   // 8 bf16 (4 VGPRs)
typedef __attribute__((ext_vector_type(4))) float f4v;    // 4 fp32 acc

static __device__ __forceinline__ int imin(int a,int b){return a<b?a:b;}
static __device__ __forceinline__ int imax(int a,int b){return a>b?a:b;}

// async global->LDS, 16B per lane; LDS dest is wave-uniform base + lane*16
__device__ __forceinline__ void gl_lds16(const float* gp, float* lp){
  __builtin_amdgcn_global_load_lds(
      (const __attribute__((address_space(1))) unsigned int*)gp,
      (__attribute__((address_space(3))) unsigned int*)lp,
      16, 0, 0);
}
__device__ __forceinline__ void gl_lds16u(const ushort_t* gp, ushort_t* lp){
  __builtin_amdgcn_global_load_lds(
      (const __attribute__((address_space(1))) unsigned int*)gp,
      (__attribute__((address_space(3))) unsigned int*)lp,
      16, 0, 0);
}

__device__ __forceinline__ ushort_t f2bf(float x){          // RNE truncate to bf16
  unsigned u = __float_as_uint(x);
  return (ushort_t)((u + 0x7FFFu + ((u>>16)&1u)) >> 16);
}
__device__ __forceinline__ float bf2f(ushort_t h){
  return __uint_as_float(((unsigned)h)<<16);
}

// ---------------- weight prep: bf16-split conv1 weights + W6 + attn transposes + zeroing ----------
// BQs[(tap*8+chunk)*5120 + n*40 + kl] = split_s( Ws[n][chunk*32+kl][tap] ), kl<32; 32..39 pad unused
__global__ __launch_bounds__(256) void k_wt(const float* __restrict__ Ws,
                                            const float* __restrict__ Whm,
                                            const float* __restrict__ Wq,
                                            const float* __restrict__ Wp2,
                                            const float* __restrict__ Wo,
                                            const float* __restrict__ Wf1,
                                            const float* __restrict__ Wf2,
                                            float* __restrict__ W6,
                                            float* __restrict__ WQT,
                                            float* __restrict__ WP2T,
                                            float* __restrict__ WOT,
                                            float* __restrict__ WF1T,
                                            float* __restrict__ WF2T,
                                            ushort_t* __restrict__ BQ0,
                                            ushort_t* __restrict__ BQ1,
                                            ushort_t* __restrict__ BQ2,
                                            int* __restrict__ Z){
  int t = blockIdx.x*256 + threadIdx.x;
  if (t < 294912){
    int kl = t & 31;
    int rest = t >> 5;
    int n = rest & 127;
    int tc = rest >> 7;            // tap*8 + chunk
    int tap = tc >> 3, chunk = tc & 7;
    int c = chunk*32 + kl;
    float v = Ws[(size_t)n*2304 + c*9 + tap];
    ushort_t h0 = f2bf(v);
    float r1 = v - bf2f(h0);
    ushort_t h1 = f2bf(r1);
    float r2 = r1 - bf2f(h1);
    ushort_t h2 = f2bf(r2);
    size_t dst = (size_t)tc*5120 + n*40 + kl;
    BQ0[dst] = h0; BQ1[dst] = h1; BQ2[dst] = h2;
  }
  if (t < 6912){
    int c = t & 127, row = t >> 7;      // row = cls*9+tap, 54 rows
    int cls = row / 9, tap = row % 9;
    W6[t] = Whm[(size_t)cls*1152 + c*9 + tap];
  }
  if (t < 16384){
    int k = t & 127, c = t >> 7;
    WQT[t]  = Wq [(size_t)k*128 + c];
    WP2T[t] = Wp2[(size_t)k*128 + c];
    WOT[t]  = Wo [(size_t)k*128 + c];
  }
  if (t < 32768){
    { int k = t & 127, o = t >> 7;  WF1T[t] = Wf1[(size_t)k*256 + o]; }
    { int k = t & 255, c = t >> 8;  WF2T[t] = Wf2[(size_t)k*128 + c]; }
  }
  if (t < 65568) Z[t] = 0;              // HIST 65536 | SCAN 16 | CNT 16
}

// ---------------- conv1 v12: split-bf16 MFMA, M=96 tiles, conflict-free A staging ----------------
// grid (264, 2): 264 = 2 i-strips(96) x 132 cols; blockIdx.y = 128-ch half.
// block 256 = 4 waves; wave w: ntiles {2w,2w+1}, all 6 M-frags. 72 MFMA per barrier-pair.
// A staged two-phase: coalesced fp32 -> LDS raw (pitch 101, conflict-free), then split-convert.
// Raw fp32 partials -> P[g]; k_cadd2 combines with bias+relu.
__global__ __launch_bounds__(256, 2) void k_conv1(const float* __restrict__ IN,
                                                  const ushort_t* __restrict__ BQ0,
                                                  const ushort_t* __restrict__ BQ1,
                                                  const ushort_t* __restrict__ BQ2,
                                                  float* __restrict__ P0,
                                                  float* __restrict__ P1){
  const int b  = blockIdx.x;
  const int g  = blockIdx.y;
  const int i0 = (b & 1) * 96;
  const int j  = b >> 1;
  const int tid = threadIdx.x;
  const int w    = tid >> 6;
  const int lane = tid & 63;
  const int l15  = lane & 15, quad = lane >> 4;
  // LDS: As 3x3920 sh | Bs 3x5120 sh | araw 3232 f  = 67168 B
  __shared__ __align__(16) ushort_t SM[33584];
  ushort_t* As0 = SM;                 // [px 98][chpad 40]
  ushort_t* As1 = SM + 3920;
  ushort_t* As2 = SM + 7840;
  ushort_t* Bs0 = SM + 11760;         // [n 128][chpad 40]
  ushort_t* Bs1 = SM + 16880;
  ushort_t* Bs2 = SM + 22000;
  float*    araw = (float*)(SM + 27120);   // [c 32][pitch 101]
  f4v acc[6][2];
  #pragma unroll
  for (int mq=0;mq<6;++mq)
    #pragma unroll
    for (int nt=0;nt<2;++nt) acc[mq][nt] = (f4v){0.f,0.f,0.f,0.f};

  for (int cq=0; cq<4; ++cq){
    const int chunk = g*4 + cq;
    for (int kw=0; kw<3; ++kw){
      __syncthreads();                 // prior tap's reads of As/Bs done
      // ---- phase 1: coalesced global -> LDS raw fp32 (stride-1 writes) ----
      {
        int gj = j - 1 + kw;
        bool jok = (unsigned)gj < 132u;
        for (int e = tid; e < 3136; e += 256){
          int c = e / 98, ii = e - c*98;
          int gi = i0 - 1 + ii;
          float v = 0.f;
          if (jok && (unsigned)gi < 192u)
            v = IN[(size_t)(chunk*32 + c)*25344 + gj*192 + gi];
          araw[c*101 + ii] = v;
        }
      }
      __syncthreads();
      // ---- phase 2: transpose + bf16-split (pitch-101 reads conflict-free; 2B-stride writes free) ----
      for (int e = tid; e < 3136; e += 256){
        int c = e & 31, ii = e >> 5;
        float v = araw[c*101 + ii];
        ushort_t h0 = f2bf(v);
        float r1 = v - bf2f(h0);
        ushort_t h1 = f2bf(r1);
        float r2 = r1 - bf2f(h1);
        ushort_t h2 = f2bf(r2);
        int a = ii*40 + c;
        As0[a] = h0; As1[a] = h1; As2[a] = h2;
      }
      for (int kh=0; kh<3; ++kh){
        if (kh > 0) __syncthreads();   // prior mfma's Bs reads done
        // ---- stage B for tap = kh*3+kw (async, padded rows preserved) ----
        {
          int tc = (kh*3 + kw)*8 + chunk;
          const ushort_t* s0 = BQ0 + (size_t)tc*5120;
          const ushort_t* s1 = BQ1 + (size_t)tc*5120;
          const ushort_t* s2 = BQ2 + (size_t)tc*5120;
          gl_lds16u(s0 + (size_t)tid*8,       Bs0 + (size_t)(w*64)*8);
          gl_lds16u(s0 + (size_t)(256+tid)*8, Bs0 + (size_t)(256 + w*64)*8);
          gl_lds16u(s1 + (size_t)tid*8,       Bs1 + (size_t)(w*64)*8);
          gl_lds16u(s1 + (size_t)(256+tid)*8, Bs1 + (size_t)(256 + w*64)*8);
          gl_lds16u(s2 + (size_t)tid*8,       Bs2 + (size_t)(w*64)*8);
          gl_lds16u(s2 + (size_t)(256+tid)*8, Bs2 + (size_t)(256 + w*64)*8);
          if (tid < 128){
            gl_lds16u(s0 + (size_t)(512+tid)*8, Bs0 + (size_t)(512 + w*64)*8);
            gl_lds16u(s1 + (size_t)(512+tid)*8, Bs1 + (size_t)(512 + w*64)*8);
            gl_lds16u(s2 + (size_t)(512+tid)*8, Bs2 + (size_t)(512 + w*64)*8);
          }
        }
        __syncthreads();               // staging visible (A for kh==0, B always)
        // ---- 6-term split-bf16 MFMA: 6 mq x 2 ntl x 6 = 72 per barrier-pair ----
        bf8v B0[2], B1[2], B2[2];
        #pragma unroll
        for (int ntl=0; ntl<2; ++ntl){
          int off = ((w*2+ntl)*16 + l15)*40 + quad*8;
          B0[ntl] = *(const bf8v*)&Bs0[off];
          B1[ntl] = *(const bf8v*)&Bs1[off];
          B2[ntl] = *(const bf8v*)&Bs2[off];
        }
        #pragma unroll
        for (int mq=0;mq<6;++mq){
          int offA = (mq*16 + l15 + kh)*40 + quad*8;
          bf8v A0 = *(const bf8v*)&As0[offA];
          bf8v A1 = *(const bf8v*)&As1[offA];
          bf8v A2 = *(const bf8v*)&As2[offA];
          #pragma unroll
          for (int ntl=0;ntl<2;++ntl){
            f4v c = acc[mq][ntl];
            c = __builtin_amdgcn_mfma_f32_16x16x32_bf16(A0, B0[ntl], c, 0,0,0);
            c = __builtin_amdgcn_mfma_f32_16x16x32_bf16(A0, B1[ntl], c, 0,0,0);
            c = __builtin_amdgcn_mfma_f32_16x16x32_bf16(A1, B0[ntl], c, 0,0,0);
            c = __builtin_amdgcn_mfma_f32_16x16x32_bf16(A0, B2[ntl], c, 0,0,0);
            c = __builtin_amdgcn_mfma_f32_16x16x32_bf16(A1, B1[ntl], c, 0,0,0);
            c = __builtin_amdgcn_mfma_f32_16x16x32_bf16(A2, B0[ntl], c, 0,0,0);
            acc[mq][ntl] = c;
          }
        }
      }
    }
  }
  // ---- epilogue: LDS transpose -> coalesced raw stores (bias+relu in k_cadd2) ----
  __syncthreads();
  float* Cs = (float*)SM;              // 96 x 128 fp32 = 49152 B <= 67168
  #pragma unroll
  for (int mq=0;mq<6;++mq)
    #pragma unroll
    for (int ntl=0;ntl<2;++ntl)
      #pragma unroll
      for (int r=0;r<4;++r){
        int m = mq*16 + quad*4 + r;          // C/D: row = quad*4+reg
        int oc = (w*2+ntl)*16 + l15;         //      col = lane&15
        Cs[m*128 + oc] = acc[mq][ntl][r];
      }
  __syncthreads();
  float* dst = g ? P1 : P0;
  for (int e = tid; e < 3072; e += 256){
    int m = e >> 5, ocq = e & 31;
    float4 v = *(float4*)&Cs[m*128 + ocq*4];
    int p = (i0 + m)*132 + j;
    *(float4*)&dst[(size_t)p*128 + ocq*4] = v;
  }
}

// ---------------- combine 2 k-split partials + bias + relu ----------------
__global__ __launch_bounds__(256) void k_cadd2(float* __restrict__ LFF,
                                               const float* __restrict__ P0,
                                               const float* __restrict__ P1,
                                               const float* __restrict__ bias){
  int t = blockIdx.x*256 + threadIdx.x;   // 3168*256 = 811008 float4s
  float4 a = ((const float4*)P0)[t];
  float4 b = ((const float4*)P1)[t];
  float4 bs = ((const float4*)bias)[t & 31];
  float4 r;
  r.x = fmaxf(a.x+b.x+bs.x, 0.f);
  r.y = fmaxf(a.y+b.y+bs.y, 0.f);
  r.z = fmaxf(a.z+b.z+bs.z, 0.f);
  r.w = fmaxf(a.w+b.w+bs.w, 0.f);
  ((float4*)LFF)[t] = r;
}

// ---------------- fused (kkvv | conv2) ; both weight paths LDS-staged (R10/R11-proven) ----------
__global__ __launch_bounds__(256) void k_mid(const float* __restrict__ LFF,
                                             const float* __restrict__ W1, const float* __restrict__ b1,
                                             const float* __restrict__ W2, const float* __restrict__ b2,
                                             const float* __restrict__ Wk, const float* __restrict__ bk,
                                             const float* __restrict__ Wv, const float* __restrict__ bv,
                                             float* __restrict__ KK, float* __restrict__ VV,
                                             const float* __restrict__ W6, const float* __restrict__ bhm,
                                             float* __restrict__ HMS){
  __shared__ float smem[12288];   // kkvv: hs 4096 | sf 4096 | wbuf 4096 (48KB)
  const int tid = threadIdx.x;
  const int wv4 = tid >> 6;
  if (blockIdx.x < 792){
    float* hs   = smem;
    float* sf   = smem + 4096;
    float* wbuf = smem + 8192;
    const int p0 = blockIdx.x*32;
    for (int e=tid; e<4096; e+=256){
      int k = e>>5, px = e&31;
      int p = p0+px;
      float bx = (float)(p/132)+0.5f, by = (float)(p%132)+0.5f;
      hs[k*32+px] = fmaxf(bx*W1[k] + by*W1[128+k] + b1[k], 0.f);
    }
    for (int e=tid; e<4096; e+=256){
      int px = e>>7, k = e&127;
      sf[k*32+px] = LFF[(size_t)(p0+px)*128 + k];
    }
    const int pxg = tid & 15, ocg = tid >> 4;   // 16 x 16
    const int px0 = pxg*2, oc0 = ocg*8;
    float accA[2][8];
    #pragma unroll
    for (int r=0;r<2;++r)
      #pragma unroll
      for (int u=0;u<8;++u) accA[r][u]=0.f;
    for (int c0=0; c0<128; c0+=32){
      __syncthreads();
      const float* wsrc = W2 + (size_t)c0*128;
      #pragma unroll
      for (int r=0;r<4;++r)
        gl_lds16(wsrc + (size_t)(r*256+tid)*4, wbuf + (size_t)(r*256+wv4*64)*4);
      __syncthreads();
      #pragma unroll 2
      for (int k=0;k<32;++k){
        float a0 = hs[(c0+k)*32+px0], a1 = hs[(c0+k)*32+px0+1];
        const float4* w = (const float4*)(wbuf + (size_t)k*128 + oc0);
        float4 w0 = w[0], w1 = w[1];
        accA[0][0]+=a0*w0.x; accA[0][1]+=a0*w0.y; accA[0][2]+=a0*w0.z; accA[0][3]+=a0*w0.w;
        accA[0][4]+=a0*w1.x; accA[0][5]+=a0*w1.y; accA[0][6]+=a0*w1.z; accA[0][7]+=a0*w1.w;
        accA[1][0]+=a1*w0.x; accA[1][1]+=a1*w0.y; accA[1][2]+=a1*w0.z; accA[1][3]+=a1*w0.w;
        accA[1][4]+=a1*w1.x; accA[1][5]+=a1*w1.y; accA[1][6]+=a1*w1.z; accA[1][7]+=a1*w1.w;
      }
    }
    __syncthreads();
    #pragma unroll
    for (int u=0;u<8;++u){
      float bb = b2[oc0+u];
      hs[(oc0+u)*32+px0]   = sf[(oc0+u)*32+px0]   + accA[0][u] + bb;
      hs[(oc0+u)*32+px0+1] = sf[(oc0+u)*32+px0+1] + accA[1][u] + bb;
    }
    float accK[2][8], accV[2][8];
    #pragma unroll
    for (int u=0;u<8;++u){
      float k0 = bk[oc0+u], v0 = bv[oc0+u];
      accK[0][u]=k0; accK[1][u]=k0; accV[0][u]=v0; accV[1][u]=v0;
    }
    for (int c0=0; c0<128; c0+=16){
      __syncthreads();
      #pragma unroll
      for (int r=0;r<2;++r){
        gl_lds16(Wk + (size_t)c0*128 + (size_t)(r*256+tid)*4, wbuf + (size_t)(r*256+wv4*64)*4);
        gl_lds16(Wv + (size_t)c0*128 + (size_t)(r*256+tid)*4, wbuf + 2048 + (size_t)(r*256+wv4*64)*4);
      }
      __syncthreads();
      #pragma unroll 2
      for (int k=0;k<16;++k){
        int kk = c0+k;
        float s0 = hs[kk*32+px0], s1 = hs[kk*32+px0+1];
        float f0 = sf[kk*32+px0], f1 = sf[kk*32+px0+1];
        const float4* wkp = (const float4*)(wbuf + (size_t)k*128 + oc0);
        const float4* wvp = (const float4*)(wbuf + 2048 + (size_t)k*128 + oc0);
        float4 k0v = wkp[0], k1v = wkp[1], v0v = wvp[0], v1v = wvp[1];
        accK[0][0]+=s0*k0v.x; accK[0][1]+=s0*k0v.y; accK[0][2]+=s0*k0v.z; accK[0][3]+=s0*k0v.w;
        accK[0][4]+=s0*k1v.x; accK[0][5]+=s0*k1v.y; accK[0][6]+=s0*k1v.z; accK[0][7]+=s0*k1v.w;
        accK[1][0]+=s1*k0v.x; accK[1][1]+=s1*k0v.y; accK[1][2]+=s1*k0v.z; accK[1][3]+=s1*k0v.w;
        accK[1][4]+=s1*k1v.x; accK[1][5]+=s1*k1v.y; accK[1][6]+=s1*k1v.z; accK[1][7]+=s1*k1v.w;
        accV[0][0]+=f0*v0v.x; accV[0][1]+=f0*v0v.y; accV[0][2]+=f0*v0v.z; accV[0][3]+=f0*v0v.w;
        accV[0][4]+=f0*v1v.x; accV[0][5]+=f0*v1v.y; accV[0][6]+=f0*v1v.z; accV[0][7]+=f0*v1v.w;
        accV[1][0]+=f1*v0v.x; accV[1][1]+=f1*v0v.y; accV[1][2]+=f1*v0v.z; accV[1][3]+=f1*v0v.w;
        accV[1][4]+=f1*v1v.x; accV[1][5]+=f1*v1v.y; accV[1][6]+=f1*v1v.z; accV[1][7]+=f1*v1v.w;
      }
    }
    #pragma unroll
    for (int r=0;r<2;++r){
      int p = p0+px0+r;
      float4* oK = (float4*)(KK + (size_t)p*128 + oc0);
      float4* oV = (float4*)(VV + (size_t)p*128 + oc0);
      float4 t0, t1;
      t0.x=accK[r][0]; t0.y=accK[r][1]; t0.z=accK[r][2]; t0.w=accK[r][3];
      t1.x=accK[r][4]; t1.y=accK[r][5]; t1.z=accK[r][6]; t1.w=accK[r][7];
      oK[0]=t0; oK[1]=t1;
      t0.x=accV[r][0]; t0.y=accV[r][1]; t0.z=accV[r][2]; t0.w=accV[r][3];
      t1.x=accV[r][4]; t1.y=accV[r][5]; t1.z=accV[r][6]; t1.w=accV[r][7];
      oV[0]=t0; oV[1]=t1;
    }
  } else {
    float* w6s = smem;          // 6912 floats
    float* red = smem + 8192;
    for (int e=tid; e<6912; e+=256) w6s[e] = W6[e];
    __syncthreads();
    int lane = tid & 63, wave = tid >> 6;
    int p = (blockIdx.x - 792)*64 + lane;        // 396*64 = 25344
    int i = p/132, j = p%132;
    float acc[6] = {0.f,0.f,0.f,0.f,0.f,0.f};
    int cbase = wave*32;
    #pragma unroll
    for (int kh=0; kh<3; ++kh){
      int gi = i+kh-1;
      if ((unsigned)gi >= 192u) continue;
      #pragma unroll
      for (int kw=0; kw<3; ++kw){
        int gj = j+kw-1;
        if ((unsigned)gj >= 132u) continue;
        const float* row = LFF + (size_t)(gi*132+gj)*128 + cbase;
        int tap = kh*3+kw;
        #pragma unroll
        for (int cq=0; cq<8; ++cq){
          float4 v = *(const float4*)(row + cq*4);
          #pragma unroll
          for (int cls=0; cls<6; ++cls){
            float4 wv = *(const float4*)(w6s + (size_t)(cls*9+tap)*128 + cbase + cq*4);
            acc[cls] += v.x*wv.x + v.y*wv.y + v.z*wv.z + v.w*wv.w;
          }
        }
      }
    }
    __syncthreads();
    #pragma unroll
    for (int c=0;c<6;++c) red[(wave*6+c)*64 + lane] = acc[c];
    __syncthreads();
    if (wave==0){
      #pragma unroll
      for (int c=0;c<6;++c){
        float s = red[c*64+lane] + red[(6+c)*64+lane] + red[(12+c)*64+lane] + red[(18+c)*64+lane] + bhm[c];
        HMS[(size_t)c*HW + p] = 1.f/(1.f+expf(-s));
      }
    }
  }
}

// ---------------- NMS + threshold + 16-bit histogram ----------------
__global__ __launch_bounds__(256) void k_nms(const float* __restrict__ HMS,
                                             float* __restrict__ VALS,
                                             int* __restrict__ HIST){
  int t = blockIdx.x*256 + threadIdx.x;   // 594*256 = 152064
  int c = t / HW, p = t % HW;
  int i = p/132, j = p%132;
  float h = HMS[t];
  float v;
  if (c < 3){
    v = 0.f;
    if (i>=1 && i<=190 && j>=1 && j<=130){
      float m = -1e30f;
      #pragma unroll
      for (int di=-1;di<=1;++di)
        #pragma unroll
        for (int dj=-1;dj<=1;++dj)
          m = fmaxf(m, HMS[(size_t)c*HW + (i+di)*132 + (j+dj)]);
      if (h == m) v = h;
    }
  } else v = h;
  if (!(v > 0.01f)) v = 0.f;
  VALS[t] = v;
  if (v > 0.f) atomicAdd(HIST + (__float_as_uint(v)>>16), 1);
}

// ---------------- level-1 scan: parallel suffix scan (R9-proven) ----------------
__global__ __launch_bounds__(1024) void k_scan(const int* __restrict__ HIST, int* __restrict__ SCAN){
  __shared__ int part[1024];
  __shared__ int gsel;
  int t = threadIdx.x;
  int s = 0, base = t*64;
  for (int u=0;u<64;++u) s += HIST[base+u];
  part[t] = s;
  __syncthreads();
  for (int off=1; off<1024; off<<=1){
    int add = (t+off < 1024) ? part[t+off] : 0;
    __syncthreads();
    part[t] += add;
    __syncthreads();
  }
  int total = part[0];
  int mineI = part[t];
  int nextI = (t < 1023) ? part[t+1] : 0;
  if (mineI >= NPROP && nextI < NPROP) gsel = t;
  if (t == 0 && total < NPROP) gsel = -1;
  __syncthreads();
  int g = gsel;
  if (g < 0){
    if (t==0){ SCAN[0] = 0; SCAN[1] = total; }
    return;
  }
  int cumG = (g < 1023) ? part[g+1] : 0;
  if (t < 64){
    int x = HIST[g*64 + t];
    #pragma unroll
    for (int off=1; off<64; off<<=1){
      int y = __shfl_down(x, off);
      x += (t + off < 64) ? y : 0;
    }
    int Snext = __shfl_down(x, 1);
    int incl  = cumG + x;
    int nextc = (t==63) ? cumG : cumG + Snext;
    if (incl >= NPROP && nextc < NPROP){
      SCAN[0] = g*64 + t;
      SCAN[1] = nextc;
    }
  }
}

// ---------------- collect candidates with bin >= bstar ----------------
__global__ __launch_bounds__(256) void k_collect(const float* __restrict__ VALS,
                                                 const int* __restrict__ SCAN,
                                                 int* __restrict__ CNT,
                                                 float* __restrict__ CV, int* __restrict__ CI){
  int t = blockIdx.x*256 + threadIdx.x;   // 594*256 = 152064
  float v = VALS[t];
  int bstar = SCAN[0];
  if (v > 0.f && (int)(__float_as_uint(v)>>16) >= bstar){
    int pos = atomicAdd(CNT, 1);
    if (pos < CAP){ CV[pos] = v; CI[pos] = t; }
  }
}

// ---------------- bitonic sort candidates (2048), take top-500 ----------------
__global__ __launch_bounds__(1024) void k_sort(const float* __restrict__ CV, const int* __restrict__ CI,
                                               const int* __restrict__ CNT,
                                               int* __restrict__ TOPS, int* __restrict__ TOPC){
  __shared__ float sv[CAP];
  __shared__ int   si[CAP];
  int tid = threadIdx.x;
  int M = imin(CNT[0], CAP);
  for (int i=tid; i<CAP; i+=1024){
    if (i < M){ sv[i] = CV[i]; si[i] = CI[i]; }
    else      { sv[i] = -1.f;  si[i] = 0x7fffffff; }
  }
  __syncthreads();
  for (int k=2; k<=CAP; k<<=1){
    for (int j=k>>1; j>0; j>>=1){
      for (int i=tid; i<CAP; i+=1024){
        int p = i ^ j;
        if (p > i){
          bool up = ((i & k) == 0);
          float va = sv[i], vb = sv[p];
          int ia = si[i], ib = si[p];
          bool aFirst = (va > vb) || (va == vb && ia < ib);
          bool bFirst = (vb > va) || (vb == va && ib < ia);
          bool doswap = up ? bFirst : aFirst;
          if (doswap){ sv[i]=vb; sv[p]=va; si[i]=ib; si[p]=ia; }
        }
      }
      __syncthreads();
    }
  }
  for (int t=tid; t<NPROP; t+=1024){
    int idx = imin(si[t], NCLS*HW - 1);
    TOPC[t] = idx / HW;
    TOPS[t] = idx % HW;
  }
}

// ---------------- fused qbuild + attention + LN/FFN/LN + heads + decode (R11-proven) ----------
__global__ __launch_bounds__(256) void k_attn(const float* __restrict__ KK, const float* __restrict__ VV,
                                              const float* __restrict__ LFF,
                                              const int* __restrict__ TOPS, const int* __restrict__ TOPC,
                                              const float* __restrict__ Wcls, const float* __restrict__ bcls,
                                              const float* __restrict__ pW1, const float* __restrict__ pb1,
                                              const float* __restrict__ WP2T, const float* __restrict__ pb2,
                                              const float* __restrict__ WQT, const float* __restrict__ bq,
                                              const float* __restrict__ WOT, const float* __restrict__ bo,
                                              const float* __restrict__ g1, const float* __restrict__ b1,
                                              const float* __restrict__ WF1T, const float* __restrict__ bf1,
                                              const float* __restrict__ WF2T, const float* __restrict__ bf2,
                                              const float* __restrict__ g2, const float* __restrict__ b2,
                                              const float* __restrict__ Wc, const float* __restrict__ bc,
                                              const float* __restrict__ Wh, const float* __restrict__ bh,
                                              const float* __restrict__ Wd, const float* __restrict__ bd,
                                              const float* __restrict__ Wr, const float* __restrict__ br,
                                              const float* __restrict__ Whm2, const float* __restrict__ bhm2,
                                              float* __restrict__ out){
  int n = blockIdx.x, tid = threadIdx.x;
  __shared__ __align__(16) float qhL[128];
  __shared__ float sc[8*441];
  __shared__ int   kiL[441];
  __shared__ __align__(16) float ctxL[128];
  __shared__ float xL[128];
  __shared__ float hidL[256];
  __shared__ float sumsL[8];
  __shared__ float stat[2];
  __shared__ float dots[16];
  int sp = TOPS[n];
  int cls = TOPC[n];
  const int kb64 = (tid>>7)*64, c128 = tid&127;
  float qreg = 0.f;
  if (tid < 128){
    float qx = (float)(sp/132)+0.5f, qy = (float)(sp%132)+0.5f;
    ctxL[tid] = fmaxf(qx*pW1[tid] + qy*pW1[128+tid] + pb1[tid], 0.f);
    qreg = LFF[(size_t)sp*128+tid] + Wcls[tid*6+cls] + bcls[tid];
  }
  __syncthreads();
  {
    const float4* wp = (const float4*)(WP2T + (size_t)c128*128 + kb64);
    float pe = 0.f;
    #pragma unroll
    for (int k4=0;k4<16;++k4){
      float4 w = wp[k4]; int kb = kb64 + k4*4;
      pe += ctxL[kb]*w.x + ctxL[kb+1]*w.y + ctxL[kb+2]*w.z + ctxL[kb+3]*w.w;
    }
    sc[tid] = pe;
  }
  __syncthreads();
  if (tid < 128) xL[tid] = qreg + pb2[tid] + sc[tid] + sc[tid+128];
  __syncthreads();
  {
    const float4* wp = (const float4*)(WQT + (size_t)c128*128 + kb64);
    float qh = 0.f;
    #pragma unroll
    for (int k4=0;k4<16;++k4){
      float4 w = wp[k4]; int kb = kb64 + k4*4;
      qh += xL[kb]*w.x + xL[kb+1]*w.y + xL[kb+2]*w.z + xL[kb+3]*w.w;
    }
    sc[tid] = qh;
  }
  __syncthreads();
  if (tid < 128) qhL[tid] = bq[tid] + sc[tid] + sc[tid+128];
  __syncthreads();
  int spx = sp/192, spy = sp%132;       // faithful to ref's //X_GRID, %Y_GRID
  for (int l = tid; l < 441; l += 256){
    int a = l/21, bb = l%21;
    int kidx = (spx + a - 10)*192 + (spy + bb - 10);
    bool msk = (kidx < 0) || (kidx >= HW);
    int kc = imin(imax(kidx,0), HW-1);
    kiL[l] = kc;
    const float4* kk4 = (const float4*)(KK + (size_t)kc*128);
    const float4* qh4 = (const float4*)qhL;
    #pragma unroll
    for (int hh=0; hh<8; ++hh){
      float acc = 0.f;
      #pragma unroll
      for (int d4=0; d4<4; ++d4){
        float4 kv = kk4[hh*4+d4]; float4 qv = qh4[hh*4+d4];
        acc += kv.x*qv.x + kv.y*qv.y + kv.z*qv.z + kv.w*qv.w;
      }
      sc[hh*441+l] = msk ? -1e9f : acc*0.25f;
    }
  }
  __syncthreads();
  int wave = tid>>6, lane = tid&63;
  for (int hh = wave; hh < 8; hh += 4){
    float mx = -3.0e38f;
    for (int l = lane; l < 441; l += 64) mx = fmaxf(mx, sc[hh*441+l]);
    #pragma unroll
    for (int off=32; off; off>>=1) mx = fmaxf(mx, __shfl_xor(mx, off));
    float sum = 0.f;
    for (int l = lane; l < 441; l += 64){
      float e = __expf(sc[hh*441+l] - mx);
      sc[hh*441+l] = e; sum += e;
    }
    #pragma unroll
    for (int off=32; off; off>>=1) sum += __shfl_xor(sum, off);
    if (lane==0) sumsL[hh] = sum;
  }
  __syncthreads();
  for (int hh = wave; hh < 8; hh += 4){
    float a[16];
    #pragma unroll
    for (int d=0; d<16; ++d) a[d]=0.f;
    for (int l = lane; l < 441; l += 64){
      float w = sc[hh*441+l];
      const float4* vv4 = (const float4*)(VV + (size_t)kiL[l]*128 + hh*16);
      #pragma unroll
      for (int d4=0; d4<4; ++d4){
        float4 v = vv4[d4];
        a[d4*4+0]+=w*v.x; a[d4*4+1]+=w*v.y; a[d4*4+2]+=w*v.z; a[d4*4+3]+=w*v.w;
      }
    }
    #pragma unroll
    for (int d=0; d<16; ++d){
      #pragma unroll
      for (int off=32; off; off>>=1) a[d] += __shfl_xor(a[d], off);
    }
    if (lane==0){
      float inv = 1.f/sumsL[hh];
      #pragma unroll
      for (int d=0; d<16; ++d) ctxL[hh*16+d] = a[d]*inv;
    }
  }
  __syncthreads();
  {
    const float4* wp = (const float4*)(WOT + (size_t)c128*128 + kb64);
    float acc = 0.f;
    #pragma unroll
    for (int k4=0;k4<16;++k4){
      float4 w = wp[k4]; int kb = kb64 + k4*4;
      acc += ctxL[kb]*w.x + ctxL[kb+1]*w.y + ctxL[kb+2]*w.z + ctxL[kb+3]*w.w;
    }
    sc[tid] = acc;
  }
  __syncthreads();
  float x1v = 0.f;
  if (tid < 128){
    x1v = qreg + bo[tid] + sc[tid] + sc[tid+128];
    xL[tid] = x1v;
  }
  __syncthreads();
  if (tid < 64){
    float u0 = xL[tid], u1 = xL[tid+64];
    float s = u0+u1, s2 = u0*u0+u1*u1;
    #pragma unroll
    for (int off=32; off; off>>=1){ s += __shfl_xor(s, off); s2 += __shfl_xor(s2, off); }
    if (tid==0){ float mean = s*(1.f/128.f); float var = s2*(1.f/128.f) - mean*mean;
      stat[0]=mean; stat[1]=rsqrtf(var + 1e-5f); }
  }
  __syncthreads();
  if (tid < 128) xL[tid] = (x1v - stat[0])*stat[1]*g1[tid] + b1[tid];
  __syncthreads();
  {
    const float4* wp = (const float4*)(WF1T + (size_t)tid*128);
    float hv = bf1[tid];
    #pragma unroll 8
    for (int k4=0;k4<32;++k4){
      float4 w = wp[k4]; int kb = k4*4;
      hv += xL[kb]*w.x + xL[kb+1]*w.y + xL[kb+2]*w.z + xL[kb+3]*w.w;
    }
    hidL[tid] = fmaxf(hv, 0.f);
  }
  __syncthreads();
  {
    int kb0 = (tid>>7)*128;
    const float4* wp = (const float4*)(WF2T + (size_t)c128*256 + kb0);
    float acc = 0.f;
    #pragma unroll 8
    for (int k4=0;k4<32;++k4){
      float4 w = wp[k4]; int kb = kb0 + k4*4;
      acc += hidL[kb]*w.x + hidL[kb+1]*w.y + hidL[kb+2]*w.z + hidL[kb+3]*w.w;
    }
    sc[tid] = acc;
  }
  __syncthreads();
  float x2v = 0.f;
  if (tid < 128) x2v = xL[tid] + bf2[tid] + sc[tid] + sc[tid+128];
  __syncthreads();
  if (tid < 128) hidL[tid] = x2v;
  __syncthreads();
  if (tid < 64){
    float u0 = hidL[tid], u1 = hidL[tid+64];
    float s = u0+u1, s2 = u0*u0+u1*u1;
    #pragma unroll
    for (int off=32; off; off>>=1){ s += __shfl_xor(s, off); s2 += __shfl_xor(s2, off); }
    if (tid==0){ float mean = s*(1.f/128.f); float var = s2*(1.f/128.f) - mean*mean;
      stat[0]=mean; stat[1]=rsqrtf(var + 1e-5f); }
  }
  __syncthreads();
  if (tid < 128) xL[tid] = (x2v - stat[0])*stat[1]*g2[tid] + b2[tid];   // final x2
  __syncthreads();
  if (tid < 14){
    const float* Wp; float bb;
    if (tid < 2)      { Wp = Wc + tid*128;        bb = bc[tid];      }
    else if (tid < 3) { Wp = Wh;                  bb = bh[0];        }
    else if (tid < 6) { Wp = Wd + (tid-3)*128;    bb = bd[tid-3];    }
    else if (tid < 8) { Wp = Wr + (tid-6)*128;    bb = br[tid-6];    }
    else              { Wp = Whm2 + (tid-8)*128;  bb = bhm2[tid-8];  }
    float acc = bb;
    for (int k=0;k<128;++k) acc += xL[k]*Wp[k];
    dots[tid] = acc;
  }
  __syncthreads();
  if (tid == 0){
    float qpx = (float)(sp/132)+0.5f, qpy = (float)(sp%132)+0.5f;
    float cx = (dots[0]+qpx)*0.64f - 61.44f;
    float cy = (dots[1]+qpy)*0.64f - 42.24f;
    float e0 = expf(dots[3]), e1 = expf(dots[4]), e2 = expf(dots[5]);
    float hgt = dots[2] - e2*0.5f;
    float rot = atanf(dots[6]/(dots[7] + 1e-6f));
    float bestv = -1.f; int bestc = 0;
    #pragma unroll
    for (int m=0;m<6;++m){
      float s = 1.f/(1.f + expf(-dots[8+m]));
      if (s > bestv){ bestv = s; bestc = m; }
    }
    float* o = out + (size_t)n*9;
    o[0]=cx; o[1]=cy; o[2]=hgt; o[3]=e0; o[4]=e1; o[5]=e2; o[6]=rot;
    o[7]=(float)bestc; o[8]=bestv;
  }
}

// ---------------- launcher ----------------
extern "C" void kernel_launch(void* const* d_in, const int* in_sizes, int n_in,
                              void* d_out, int out_size, void* d_ws, size_t ws_size,
                              hipStream_t stream){
  (void)in_sizes; (void)n_in; (void)out_size;
  const float* IN   = (const float*)d_in[0];
  const float* Wsh  = (const float*)d_in[1];
  const float* bsh  = (const float*)d_in[2];
  const float* Whm  = (const float*)d_in[3];
  const float* bhm  = (const float*)d_in[4];
  const float* Wcls = (const float*)d_in[5];
  const float* bcls = (const float*)d_in[6];
  const float* Wp1  = (const float*)d_in[7];
  const float* bp1  = (const float*)d_in[8];
  const float* Wp2  = (const float*)d_in[9];
  const float* bp2  = (const float*)d_in[10];
  const float* Wq   = (const float*)d_in[11];
  const float* bq   = (const float*)d_in[12];
  const float* Wk   = (const float*)d_in[13];
  const float* bk   = (const float*)d_in[14];
  const float* Wv   = (const float*)d_in[15];
  const float* bv   = (const float*)d_in[16];
  const float* Wo   = (const float*)d_in[17];
  const float* bo   = (const float*)d_in[18];
  const float* g1   = (const float*)d_in[19];
  const float* b1   = (const float*)d_in[20];
  const float* g2   = (const float*)d_in[21];
  const float* b2   = (const float*)d_in[22];
  const float* Wf1  = (const float*)d_in[23];
  const float* bf1  = (const float*)d_in[24];
  const float* Wf2  = (const float*)d_in[25];
  const float* bf2  = (const float*)d_in[26];
  const float* Wc   = (const float*)d_in[27];
  const float* bc   = (const float*)d_in[28];
  const float* Wh   = (const float*)d_in[29];
  const float* bh   = (const float*)d_in[30];
  const float* Wd   = (const float*)d_in[31];
  const float* bd   = (const float*)d_in[32];
  const float* Wr   = (const float*)d_in[33];
  const float* br   = (const float*)d_in[34];
  const float* Whm2 = (const float*)d_in[37];
  const float* bhm2 = (const float*)d_in[38];
  float* out = (float*)d_out;
  float* W = (float*)d_ws;

  const size_t N_LFF  = (size_t)HW*128;
  const size_t OFF_LFF  = 0;
  const size_t OFF_KK   = OFF_LFF + N_LFF;         // conv1 partial P0, then KK
  const size_t OFF_VV   = OFF_KK + N_LFF;          // conv1 partial P1, then VV
  const size_t OFF_W6   = OFF_VV + N_LFF;          // 6912
  const size_t OFF_HMS  = OFF_W6 + 6912;           // 152064
  const size_t OFF_VALS = OFF_HMS + 152064;        // 152064
  const size_t OFF_HIST = OFF_VALS + 152064;       // 65536
  const size_t OFF_SCAN = OFF_HIST + 65536;        // 16
  const size_t OFF_CNT  = OFF_SCAN + 16;           // 16
  const size_t OFF_CV   = OFF_CNT + 16;            // CAP
  const size_t OFF_CI   = OFF_CV + CAP;            // CAP
  const size_t OFF_TOPS = OFF_CI + CAP;            // 512
  const size_t OFF_TOPC = OFF_TOPS + 512;          // 512
  const size_t OFF_WQT  = OFF_TOPC + 512;          // 16384
  const size_t OFF_WP2T = OFF_WQT + 16384;         // 16384
  const size_t OFF_WOT  = OFF_WP2T + 16384;        // 16384
  const size_t OFF_WF1T = OFF_WOT + 16384;         // 32768
  const size_t OFF_WF2T = OFF_WF1T + 32768;        // 32768
  const size_t OFF_BQ0  = OFF_WF2T + 32768;        // 184320 floats (= 368640 bf16)
  const size_t OFF_BQ1  = OFF_BQ0 + 184320;
  const size_t OFF_BQ2  = OFF_BQ1 + 184320;
  const size_t TOTAL    = OFF_BQ2 + 184320;
  if (ws_size < TOTAL*sizeof(float)) return;

  ushort_t* BQ0 = (ushort_t*)(W + OFF_BQ0);
  ushort_t* BQ1 = (ushort_t*)(W + OFF_BQ1);
  ushort_t* BQ2 = (ushort_t*)(W + OFF_BQ2);

  // k_wt also zeroes HIST|SCAN|CNT (65568 ints, contiguous at OFF_HIST)
  k_wt    <<<1152, 256, 0, stream>>>(Wsh, Whm, Wq, Wp2, Wo, Wf1, Wf2,
                                     W+OFF_W6,
                                     W+OFF_WQT, W+OFF_WP2T, W+OFF_WOT, W+OFF_WF1T, W+OFF_WF2T,
                                     BQ0, BQ1, BQ2,
                                     (int*)(W+OFF_HIST));
  k_conv1 <<<dim3(264,2), 256, 0, stream>>>(IN, BQ0, BQ1, BQ2, W+OFF_KK, W+OFF_VV);
  k_cadd2 <<<3168, 256, 0, stream>>>(W+OFF_LFF, W+OFF_KK, W+OFF_VV, bsh);
  k_mid   <<<1188, 256, 0, stream>>>(W+OFF_LFF, Wp1, bp1, Wp2, bp2, Wk, bk, Wv, bv,
                                     W+OFF_KK, W+OFF_VV, W+OFF_W6, bhm, W+OFF_HMS);
  k_nms   <<<594,  256, 0, stream>>>(W+OFF_HMS, W+OFF_VALS, (int*)(W+OFF_HIST));
  k_scan  <<<1,   1024, 0, stream>>>((const int*)(W+OFF_HIST), (int*)(W+OFF_SCAN));
  k_collect<<<594, 256, 0, stream>>>(W+OFF_VALS, (const int*)(W+OFF_SCAN),
                                     (int*)(W+OFF_CNT), W+OFF_CV, (int*)(W+OFF_CI));
  k_sort  <<<1,   1024, 0, stream>>>(W+OFF_CV, (const int*)(W+OFF_CI), (const int*)(W+OFF_CNT),
                                     (int*)(W+OFF_TOPS), (int*)(W+OFF_TOPC));
  k_attn  <<<500,  256, 0, stream>>>(W+OFF_KK, W+OFF_VV, W+OFF_LFF,
                                     (const int*)(W+OFF_TOPS), (const int*)(W+OFF_TOPC),
                                     Wcls, bcls, Wp1, bp1, W+OFF_WP2T, bp2, W+OFF_WQT, bq,
                                     W+OFF_WOT, bo, g1, b1, W+OFF_WF1T, bf1, W+OFF_WF2T, bf2, g2, b2,
                                     Wc, bc, Wh, bh, Wd, bd, Wr, br, Whm2, bhm2, out);
}

// Round 15
// 549.171 us; speedup vs baseline: 1.0767x; 1.0767x over previous
//
#include <hip/hip_runtime.h>
#include <math.h>
#include <float.h>

#define XG 192
#define YG 132
#define HW 25344           // 192*132
#define NCLS 6
#define NPROP 500
#define LWIN 441
#define CAP 2048           // candidate cap for top-k sort (one-level select)

typedef unsigned short ushort_t;
typedef __attribute__((ext_vector_type(8))) short bf8v;   // 8 bf16 (4 VGPRs)
typedef __attribute__((ext_vector_type(4))) float f4v;    // 4 fp32 acc

static __device__ __forceinline__ int imin(int a,int b){return a<b?a:b;}
static __device__ __forceinline__ int imax(int a,int b){return a>b?a:b;}

// async global->LDS, 16B per lane; LDS dest is wave-uniform base + lane*16
__device__ __forceinline__ void gl_lds16(const float* gp, float* lp){
  __builtin_amdgcn_global_load_lds(
      (const __attribute__((address_space(1))) unsigned int*)gp,
      (__attribute__((address_space(3))) unsigned int*)lp,
      16, 0, 0);
}
__device__ __forceinline__ void gl_lds16u(const ushort_t* gp, ushort_t* lp){
  __builtin_amdgcn_global_load_lds(
      (const __attribute__((address_space(1))) unsigned int*)gp,
      (__attribute__((address_space(3))) unsigned int*)lp,
      16, 0, 0);
}

__device__ __forceinline__ ushort_t f2bf(float x){          // RNE truncate to bf16
  unsigned u = __float_as_uint(x);
  return (ushort_t)((u + 0x7FFFu + ((u>>16)&1u)) >> 16);
}
__device__ __forceinline__ float bf2f(ushort_t h){
  return __uint_as_float(((unsigned)h)<<16);
}

// ---------------- weight prep: bf16-split conv1 weights + W6 + attn transposes + zeroing ----------
__global__ __launch_bounds__(256) void k_wt(const float* __restrict__ Ws,
                                            const float* __restrict__ Whm,
                                            const float* __restrict__ Wq,
                                            const float* __restrict__ Wp2,
                                            const float* __restrict__ Wo,
                                            const float* __restrict__ Wf1,
                                            const float* __restrict__ Wf2,
                                            float* __restrict__ W6,
                                            float* __restrict__ WQT,
                                            float* __restrict__ WP2T,
                                            float* __restrict__ WOT,
                                            float* __restrict__ WF1T,
                                            float* __restrict__ WF2T,
                                            ushort_t* __restrict__ BQ0,
                                            ushort_t* __restrict__ BQ1,
                                            ushort_t* __restrict__ BQ2,
                                            int* __restrict__ Z){
  int t = blockIdx.x*256 + threadIdx.x;
  if (t < 294912){
    int kl = t & 31;
    int rest = t >> 5;
    int n = rest & 127;
    int tc = rest >> 7;            // tap*8 + chunk
    int tap = tc >> 3, chunk = tc & 7;
    int c = chunk*32 + kl;
    float v = Ws[(size_t)n*2304 + c*9 + tap];
    ushort_t h0 = f2bf(v);
    float r1 = v - bf2f(h0);
    ushort_t h1 = f2bf(r1);
    float r2 = r1 - bf2f(h1);
    ushort_t h2 = f2bf(r2);
    size_t dst = (size_t)tc*5120 + n*40 + kl;
    BQ0[dst] = h0; BQ1[dst] = h1; BQ2[dst] = h2;
  }
  if (t < 6912){
    int c = t & 127, row = t >> 7;      // row = cls*9+tap, 54 rows
    int cls = row / 9, tap = row % 9;
    W6[t] = Whm[(size_t)cls*1152 + c*9 + tap];
  }
  if (t < 16384){
    int k = t & 127, c = t >> 7;
    WQT[t]  = Wq [(size_t)k*128 + c];
    WP2T[t] = Wp2[(size_t)k*128 + c];
    WOT[t]  = Wo [(size_t)k*128 + c];
  }
  if (t < 32768){
    { int k = t & 127, o = t >> 7;  WF1T[t] = Wf1[(size_t)k*256 + o]; }
    { int k = t & 255, c = t >> 8;  WF2T[t] = Wf2[(size_t)k*128 + c]; }
  }
  if (t < 65568) Z[t] = 0;              // HIST 65536 | SCAN 16 | CNT 16
}

// ---------------- conv1 v11 (R13-proven 170us): split-bf16 MFMA, K-split x2, M=64 ----------------
// R14 lesson: M=96 @ 65.6KB LDS regressed (occ 12%); keep 46.6KB / 3-resident shape.
__global__ __launch_bounds__(256, 3) void k_conv1(const float* __restrict__ IN,
                                                  const ushort_t* __restrict__ BQ0,
                                                  const ushort_t* __restrict__ BQ1,
                                                  const ushort_t* __restrict__ BQ2,
                                                  float* __restrict__ P0,
                                                  float* __restrict__ P1){
  const int b  = blockIdx.x;
  const int g  = blockIdx.y;
  const int i0 = (b % 3) * 64;
  const int j  = b / 3;
  const int tid = threadIdx.x;
  const int w    = tid >> 6;
  const int lane = tid & 63;
  const int l15  = lane & 15, quad = lane >> 4;
  __shared__ __align__(16) ushort_t SM[23280];   // A: 3x2640 | B: 3x5120 (46560 B)
  ushort_t* As0 = SM;                 // [px 66][chpad 40]
  ushort_t* As1 = SM + 2640;
  ushort_t* As2 = SM + 5280;
  ushort_t* Bs0 = SM + 7920;          // [n 128][chpad 40]
  ushort_t* Bs1 = SM + 13040;
  ushort_t* Bs2 = SM + 18160;
  f4v acc[4][2];
  #pragma unroll
  for (int mq=0;mq<4;++mq)
    #pragma unroll
    for (int nt=0;nt<2;++nt) acc[mq][nt] = (f4v){0.f,0.f,0.f,0.f};

  for (int cq=0; cq<4; ++cq){
    const int chunk = g*4 + cq;
    for (int kw=0; kw<3; ++kw){
      __syncthreads();                 // prior tap's reads of As/Bs done
      {
        int gj = j - 1 + kw;
        bool jok = (unsigned)gj < 132u;
        for (int e = tid; e < 2112; e += 256){
          int c = e / 66, ii = e - c*66;
          int gi = i0 - 1 + ii;
          float v = 0.f;
          if (jok && (unsigned)gi < 192u)
            v = IN[(size_t)(chunk*32 + c)*25344 + gj*192 + gi];
          ushort_t h0 = f2bf(v);
          float r1 = v - bf2f(h0);
          ushort_t h1 = f2bf(r1);
          float r2 = r1 - bf2f(h1);
          ushort_t h2 = f2bf(r2);
          int a = ii*40 + c;
          As0[a] = h0; As1[a] = h1; As2[a] = h2;
        }
      }
      for (int kh=0; kh<3; ++kh){
        if (kh > 0) __syncthreads();   // prior mfma's Bs reads done
        {
          int tc = (kh*3 + kw)*8 + chunk;
          const ushort_t* s0 = BQ0 + (size_t)tc*5120;
          const ushort_t* s1 = BQ1 + (size_t)tc*5120;
          const ushort_t* s2 = BQ2 + (size_t)tc*5120;
          gl_lds16u(s0 + (size_t)tid*8,       Bs0 + (size_t)(w*64)*8);
          gl_lds16u(s0 + (size_t)(256+tid)*8, Bs0 + (size_t)(256 + w*64)*8);
          gl_lds16u(s1 + (size_t)tid*8,       Bs1 + (size_t)(w*64)*8);
          gl_lds16u(s1 + (size_t)(256+tid)*8, Bs1 + (size_t)(256 + w*64)*8);
          gl_lds16u(s2 + (size_t)tid*8,       Bs2 + (size_t)(w*64)*8);
          gl_lds16u(s2 + (size_t)(256+tid)*8, Bs2 + (size_t)(256 + w*64)*8);
          if (tid < 128){
            gl_lds16u(s0 + (size_t)(512+tid)*8, Bs0 + (size_t)(512 + w*64)*8);
            gl_lds16u(s1 + (size_t)(512+tid)*8, Bs1 + (size_t)(512 + w*64)*8);
            gl_lds16u(s2 + (size_t)(512+tid)*8, Bs2 + (size_t)(512 + w*64)*8);
          }
        }
        __syncthreads();               // staging visible (A for kh==0, B always)
        bf8v A0[4], A1[4], A2[4];
        #pragma unroll
        for (int mq=0; mq<4; ++mq){
          int off = (mq*16 + l15 + kh)*40 + quad*8;
          A0[mq] = *(const bf8v*)&As0[off];
          A1[mq] = *(const bf8v*)&As1[off];
          A2[mq] = *(const bf8v*)&As2[off];
        }
        bf8v B0[2], B1[2], B2[2];
        #pragma unroll
        for (int ntl=0; ntl<2; ++ntl){
          int off = ((w*2+ntl)*16 + l15)*40 + quad*8;
          B0[ntl] = *(const bf8v*)&Bs0[off];
          B1[ntl] = *(const bf8v*)&Bs1[off];
          B2[ntl] = *(const bf8v*)&Bs2[off];
        }
        #pragma unroll
        for (int mq=0;mq<4;++mq){
          #pragma unroll
          for (int ntl=0;ntl<2;++ntl){
            f4v c = acc[mq][ntl];
            c = __builtin_amdgcn_mfma_f32_16x16x32_bf16(A0[mq], B0[ntl], c, 0,0,0);
            c = __builtin_amdgcn_mfma_f32_16x16x32_bf16(A0[mq], B1[ntl], c, 0,0,0);
            c = __builtin_amdgcn_mfma_f32_16x16x32_bf16(A1[mq], B0[ntl], c, 0,0,0);
            c = __builtin_amdgcn_mfma_f32_16x16x32_bf16(A0[mq], B2[ntl], c, 0,0,0);
            c = __builtin_amdgcn_mfma_f32_16x16x32_bf16(A1[mq], B1[ntl], c, 0,0,0);
            c = __builtin_amdgcn_mfma_f32_16x16x32_bf16(A2[mq], B0[ntl], c, 0,0,0);
            acc[mq][ntl] = c;
          }
        }
      }
    }
  }
  __syncthreads();
  float* Cs = (float*)SM;              // 64 x 128 fp32 = 32768 B <= 46560
  #pragma unroll
  for (int mq=0;mq<4;++mq)
    #pragma unroll
    for (int ntl=0;ntl<2;++ntl)
      #pragma unroll
      for (int r=0;r<4;++r){
        int m = mq*16 + quad*4 + r;          // C/D: row = quad*4+reg
        int oc = (w*2+ntl)*16 + l15;         //      col = lane&15
        Cs[m*128 + oc] = acc[mq][ntl][r];
      }
  __syncthreads();
  float* dst = g ? P1 : P0;
  for (int e = tid; e < 2048; e += 256){
    int m = e >> 5, ocq = e & 31;
    float4 v = *(float4*)&Cs[m*128 + ocq*4];
    int p = (i0 + m)*132 + j;
    *(float4*)&dst[(size_t)p*128 + ocq*4] = v;
  }
}

// ---------------- combine 2 k-split partials + bias + relu ----------------
__global__ __launch_bounds__(256) void k_cadd2(float* __restrict__ LFF,
                                               const float* __restrict__ P0,
                                               const float* __restrict__ P1,
                                               const float* __restrict__ bias){
  int t = blockIdx.x*256 + threadIdx.x;   // 3168*256 = 811008 float4s
  float4 a = ((const float4*)P0)[t];
  float4 b = ((const float4*)P1)[t];
  float4 bs = ((const float4*)bias)[t & 31];
  float4 r;
  r.x = fmaxf(a.x+b.x+bs.x, 0.f);
  r.y = fmaxf(a.y+b.y+bs.y, 0.f);
  r.z = fmaxf(a.z+b.z+bs.z, 0.f);
  r.w = fmaxf(a.w+b.w+bs.w, 0.f);
  ((float4*)LFF)[t] = r;
}

// ---------------- fused (kkvv | conv2) ; both weight paths LDS-staged (R10/R11-proven) ----------
__global__ __launch_bounds__(256) void k_mid(const float* __restrict__ LFF,
                                             const float* __restrict__ W1, const float* __restrict__ b1,
                                             const float* __restrict__ W2, const float* __restrict__ b2,
                                             const float* __restrict__ Wk, const float* __restrict__ bk,
                                             const float* __restrict__ Wv, const float* __restrict__ bv,
                                             float* __restrict__ KK, float* __restrict__ VV,
                                             const float* __restrict__ W6, const float* __restrict__ bhm,
                                             float* __restrict__ HMS){
  __shared__ float smem[12288];   // kkvv: hs 4096 | sf 4096 | wbuf 4096 (48KB)
  const int tid = threadIdx.x;
  const int wv4 = tid >> 6;
  if (blockIdx.x < 792){
    float* hs   = smem;
    float* sf   = smem + 4096;
    float* wbuf = smem + 8192;
    const int p0 = blockIdx.x*32;
    for (int e=tid; e<4096; e+=256){
      int k = e>>5, px = e&31;
      int p = p0+px;
      float bx = (float)(p/132)+0.5f, by = (float)(p%132)+0.5f;
      hs[k*32+px] = fmaxf(bx*W1[k] + by*W1[128+k] + b1[k], 0.f);
    }
    for (int e=tid; e<4096; e+=256){
      int px = e>>7, k = e&127;
      sf[k*32+px] = LFF[(size_t)(p0+px)*128 + k];
    }
    const int pxg = tid & 15, ocg = tid >> 4;   // 16 x 16
    const int px0 = pxg*2, oc0 = ocg*8;
    float accA[2][8];
    #pragma unroll
    for (int r=0;r<2;++r)
      #pragma unroll
      for (int u=0;u<8;++u) accA[r][u]=0.f;
    for (int c0=0; c0<128; c0+=32){
      __syncthreads();
      const float* wsrc = W2 + (size_t)c0*128;
      #pragma unroll
      for (int r=0;r<4;++r)
        gl_lds16(wsrc + (size_t)(r*256+tid)*4, wbuf + (size_t)(r*256+wv4*64)*4);
      __syncthreads();
      #pragma unroll 2
      for (int k=0;k<32;++k){
        float a0 = hs[(c0+k)*32+px0], a1 = hs[(c0+k)*32+px0+1];
        const float4* w = (const float4*)(wbuf + (size_t)k*128 + oc0);
        float4 w0 = w[0], w1 = w[1];
        accA[0][0]+=a0*w0.x; accA[0][1]+=a0*w0.y; accA[0][2]+=a0*w0.z; accA[0][3]+=a0*w0.w;
        accA[0][4]+=a0*w1.x; accA[0][5]+=a0*w1.y; accA[0][6]+=a0*w1.z; accA[0][7]+=a0*w1.w;
        accA[1][0]+=a1*w0.x; accA[1][1]+=a1*w0.y; accA[1][2]+=a1*w0.z; accA[1][3]+=a1*w0.w;
        accA[1][4]+=a1*w1.x; accA[1][5]+=a1*w1.y; accA[1][6]+=a1*w1.z; accA[1][7]+=a1*w1.w;
      }
    }
    __syncthreads();
    #pragma unroll
    for (int u=0;u<8;++u){
      float bb = b2[oc0+u];
      hs[(oc0+u)*32+px0]   = sf[(oc0+u)*32+px0]   + accA[0][u] + bb;
      hs[(oc0+u)*32+px0+1] = sf[(oc0+u)*32+px0+1] + accA[1][u] + bb;
    }
    float accK[2][8], accV[2][8];
    #pragma unroll
    for (int u=0;u<8;++u){
      float k0 = bk[oc0+u], v0 = bv[oc0+u];
      accK[0][u]=k0; accK[1][u]=k0; accV[0][u]=v0; accV[1][u]=v0;
    }
    for (int c0=0; c0<128; c0+=16){
      __syncthreads();
      #pragma unroll
      for (int r=0;r<2;++r){
        gl_lds16(Wk + (size_t)c0*128 + (size_t)(r*256+tid)*4, wbuf + (size_t)(r*256+wv4*64)*4);
        gl_lds16(Wv + (size_t)c0*128 + (size_t)(r*256+tid)*4, wbuf + 2048 + (size_t)(r*256+wv4*64)*4);
      }
      __syncthreads();
      #pragma unroll 2
      for (int k=0;k<16;++k){
        int kk = c0+k;
        float s0 = hs[kk*32+px0], s1 = hs[kk*32+px0+1];
        float f0 = sf[kk*32+px0], f1 = sf[kk*32+px0+1];
        const float4* wkp = (const float4*)(wbuf + (size_t)k*128 + oc0);
        const float4* wvp = (const float4*)(wbuf + 2048 + (size_t)k*128 + oc0);
        float4 k0v = wkp[0], k1v = wkp[1], v0v = wvp[0], v1v = wvp[1];
        accK[0][0]+=s0*k0v.x; accK[0][1]+=s0*k0v.y; accK[0][2]+=s0*k0v.z; accK[0][3]+=s0*k0v.w;
        accK[0][4]+=s0*k1v.x; accK[0][5]+=s0*k1v.y; accK[0][6]+=s0*k1v.z; accK[0][7]+=s0*k1v.w;
        accK[1][0]+=s1*k0v.x; accK[1][1]+=s1*k0v.y; accK[1][2]+=s1*k0v.z; accK[1][3]+=s1*k0v.w;
        accK[1][4]+=s1*k1v.x; accK[1][5]+=s1*k1v.y; accK[1][6]+=s1*k1v.z; accK[1][7]+=s1*k1v.w;
        accV[0][0]+=f0*v0v.x; accV[0][1]+=f0*v0v.y; accV[0][2]+=f0*v0v.z; accV[0][3]+=f0*v0v.w;
        accV[0][4]+=f0*v1v.x; accV[0][5]+=f0*v1v.y; accV[0][6]+=f0*v1v.z; accV[0][7]+=f0*v1v.w;
        accV[1][0]+=f1*v0v.x; accV[1][1]+=f1*v0v.y; accV[1][2]+=f1*v0v.z; accV[1][3]+=f1*v0v.w;
        accV[1][4]+=f1*v1v.x; accV[1][5]+=f1*v1v.y; accV[1][6]+=f1*v1v.z; accV[1][7]+=f1*v1v.w;
      }
    }
    #pragma unroll
    for (int r=0;r<2;++r){
      int p = p0+px0+r;
      float4* oK = (float4*)(KK + (size_t)p*128 + oc0);
      float4* oV = (float4*)(VV + (size_t)p*128 + oc0);
      float4 t0, t1;
      t0.x=accK[r][0]; t0.y=accK[r][1]; t0.z=accK[r][2]; t0.w=accK[r][3];
      t1.x=accK[r][4]; t1.y=accK[r][5]; t1.z=accK[r][6]; t1.w=accK[r][7];
      oK[0]=t0; oK[1]=t1;
      t0.x=accV[r][0]; t0.y=accV[r][1]; t0.z=accV[r][2]; t0.w=accV[r][3];
      t1.x=accV[r][4]; t1.y=accV[r][5]; t1.z=accV[r][6]; t1.w=accV[r][7];
      oV[0]=t0; oV[1]=t1;
    }
  } else {
    float* w6s = smem;          // 6912 floats
    float* red = smem + 8192;
    for (int e=tid; e<6912; e+=256) w6s[e] = W6[e];
    __syncthreads();
    int lane = tid & 63, wave = tid >> 6;
    int p = (blockIdx.x - 792)*64 + lane;        // 396*64 = 25344
    int i = p/132, j = p%132;
    float acc[6] = {0.f,0.f,0.f,0.f,0.f,0.f};
    int cbase = wave*32;
    #pragma unroll
    for (int kh=0; kh<3; ++kh){
      int gi = i+kh-1;
      if ((unsigned)gi >= 192u) continue;
      #pragma unroll
      for (int kw=0; kw<3; ++kw){
        int gj = j+kw-1;
        if ((unsigned)gj >= 132u) continue;
        const float* row = LFF + (size_t)(gi*132+gj)*128 + cbase;
        int tap = kh*3+kw;
        #pragma unroll
        for (int cq=0; cq<8; ++cq){
          float4 v = *(const float4*)(row + cq*4);
          #pragma unroll
          for (int cls=0; cls<6; ++cls){
            float4 wv = *(const float4*)(w6s + (size_t)(cls*9+tap)*128 + cbase + cq*4);
            acc[cls] += v.x*wv.x + v.y*wv.y + v.z*wv.z + v.w*wv.w;
          }
        }
      }
    }
    __syncthreads();
    #pragma unroll
    for (int c=0;c<6;++c) red[(wave*6+c)*64 + lane] = acc[c];
    __syncthreads();
    if (wave==0){
      #pragma unroll
      for (int c=0;c<6;++c){
        float s = red[c*64+lane] + red[(6+c)*64+lane] + red[(12+c)*64+lane] + red[(18+c)*64+lane] + bhm[c];
        HMS[(size_t)c*HW + p] = 1.f/(1.f+expf(-s));
      }
    }
  }
}

// ---------------- NMS + threshold + 16-bit histogram ----------------
__global__ __launch_bounds__(256) void k_nms(const float* __restrict__ HMS,
                                             float* __restrict__ VALS,
                                             int* __restrict__ HIST){
  int t = blockIdx.x*256 + threadIdx.x;   // 594*256 = 152064
  int c = t / HW, p = t % HW;
  int i = p/132, j = p%132;
  float h = HMS[t];
  float v;
  if (c < 3){
    v = 0.f;
    if (i>=1 && i<=190 && j>=1 && j<=130){
      float m = -1e30f;
      #pragma unroll
      for (int di=-1;di<=1;++di)
        #pragma unroll
        for (int dj=-1;dj<=1;++dj)
          m = fmaxf(m, HMS[(size_t)c*HW + (i+di)*132 + (j+dj)]);
      if (h == m) v = h;
    }
  } else v = h;
  if (!(v > 0.01f)) v = 0.f;
  VALS[t] = v;
  if (v > 0.f) atomicAdd(HIST + (__float_as_uint(v)>>16), 1);
}

// ---------------- level-1 scan: parallel suffix scan (R9-proven) ----------------
__global__ __launch_bounds__(1024) void k_scan(const int* __restrict__ HIST, int* __restrict__ SCAN){
  __shared__ int part[1024];
  __shared__ int gsel;
  int t = threadIdx.x;
  int s = 0, base = t*64;
  for (int u=0;u<64;++u) s += HIST[base+u];
  part[t] = s;
  __syncthreads();
  for (int off=1; off<1024; off<<=1){
    int add = (t+off < 1024) ? part[t+off] : 0;
    __syncthreads();
    part[t] += add;
    __syncthreads();
  }
  int total = part[0];
  int mineI = part[t];
  int nextI = (t < 1023) ? part[t+1] : 0;
  if (mineI >= NPROP && nextI < NPROP) gsel = t;
  if (t == 0 && total < NPROP) gsel = -1;
  __syncthreads();
  int g = gsel;
  if (g < 0){
    if (t==0){ SCAN[0] = 0; SCAN[1] = total; }
    return;
  }
  int cumG = (g < 1023) ? part[g+1] : 0;
  if (t < 64){
    int x = HIST[g*64 + t];
    #pragma unroll
    for (int off=1; off<64; off<<=1){
      int y = __shfl_down(x, off);
      x += (t + off < 64) ? y : 0;
    }
    int Snext = __shfl_down(x, 1);
    int incl  = cumG + x;
    int nextc = (t==63) ? cumG : cumG + Snext;
    if (incl >= NPROP && nextc < NPROP){
      SCAN[0] = g*64 + t;
      SCAN[1] = nextc;
    }
  }
}

// ---------------- collect candidates with bin >= bstar ----------------
__global__ __launch_bounds__(256) void k_collect(const float* __restrict__ VALS,
                                                 const int* __restrict__ SCAN,
                                                 int* __restrict__ CNT,
                                                 float* __restrict__ CV, int* __restrict__ CI){
  int t = blockIdx.x*256 + threadIdx.x;   // 594*256 = 152064
  float v = VALS[t];
  int bstar = SCAN[0];
  if (v > 0.f && (int)(__float_as_uint(v)>>16) >= bstar){
    int pos = atomicAdd(CNT, 1);
    if (pos < CAP){ CV[pos] = v; CI[pos] = t; }
  }
}

// ---------------- bitonic sort (2048) -> top-500; then spatial re-sort by sp with rank perm ------
__global__ __launch_bounds__(1024) void k_sort(const float* __restrict__ CV, const int* __restrict__ CI,
                                               const int* __restrict__ CNT,
                                               int* __restrict__ TOPS, int* __restrict__ TOPC,
                                               int* __restrict__ RANK){
  __shared__ float sv[CAP];
  __shared__ int   si[CAP];
  __shared__ int   keyA[512];
  __shared__ int   clsA[512];
  int tid = threadIdx.x;
  int M = imin(CNT[0], CAP);
  for (int i=tid; i<CAP; i+=1024){
    if (i < M){ sv[i] = CV[i]; si[i] = CI[i]; }
    else      { sv[i] = -1.f;  si[i] = 0x7fffffff; }
  }
  __syncthreads();
  for (int k=2; k<=CAP; k<<=1){
    for (int j=k>>1; j>0; j>>=1){
      for (int i=tid; i<CAP; i+=1024){
        int p = i ^ j;
        if (p > i){
          bool up = ((i & k) == 0);
          float va = sv[i], vb = sv[p];
          int ia = si[i], ib = si[p];
          bool aFirst = (va > vb) || (va == vb && ia < ib);
          bool bFirst = (vb > va) || (vb == va && ib < ia);
          bool doswap = up ? bFirst : aFirst;
          if (doswap){ sv[i]=vb; sv[p]=va; si[i]=ib; si[p]=ia; }
        }
      }
      __syncthreads();
    }
  }
  // build (sp, rank) keys for spatial sort; sentinels for t >= 500
  if (tid < 512){
    if (tid < NPROP){
      int idx = imin(si[tid], NCLS*HW - 1);
      keyA[tid] = (idx % HW)*512 + tid;    // sp<25344, rank<512 -> 24 bits
      clsA[tid] = idx / HW;
    } else { keyA[tid] = 0x7fffffff; clsA[tid] = 0; }
  }
  __syncthreads();
  for (int k=2; k<=512; k<<=1){
    for (int j=k>>1; j>0; j>>=1){
      if (tid < 512){
        int i = tid, p = i ^ j;
        if (p > i){
          bool up = ((i & k) == 0);        // ascending by key
          int ka = keyA[i], kb = keyA[p];
          bool doswap = up ? (ka > kb) : (ka < kb);
          if (doswap){ keyA[i]=kb; keyA[p]=ka; }
        }
      }
      __syncthreads();
    }
  }
  if (tid < 512){
    int k = keyA[tid];
    int r = k & 511;
    TOPS[tid] = k >> 9;
    TOPC[tid] = clsA[r];
    RANK[tid] = r;
  }
}

// ---------------- fused qbuild + attention + LN/FFN/LN + heads + decode; 512 threads ----------
// Block processes spatially-sorted proposal n=(bx&7)*64+(bx>>3) (XCD-aware swizzle for KK/VV L2
// locality); writes output row RANK[n]. One head per wave; 4-way split-k GEMVs.
__global__ __launch_bounds__(512) void k_attn(const float* __restrict__ KK, const float* __restrict__ VV,
                                              const float* __restrict__ LFF,
                                              const int* __restrict__ TOPS, const int* __restrict__ TOPC,
                                              const int* __restrict__ RANK,
                                              const float* __restrict__ Wcls, const float* __restrict__ bcls,
                                              const float* __restrict__ pW1, const float* __restrict__ pb1,
                                              const float* __restrict__ WP2T, const float* __restrict__ pb2,
                                              const float* __restrict__ WQT, const float* __restrict__ bq,
                                              const float* __restrict__ WOT, const float* __restrict__ bo,
                                              const float* __restrict__ g1, const float* __restrict__ b1,
                                              const float* __restrict__ WF1T, const float* __restrict__ bf1,
                                              const float* __restrict__ WF2T, const float* __restrict__ bf2,
                                              const float* __restrict__ g2, const float* __restrict__ b2,
                                              const float* __restrict__ Wc, const float* __restrict__ bc,
                                              const float* __restrict__ Wh, const float* __restrict__ bh,
                                              const float* __restrict__ Wd, const float* __restrict__ bd,
                                              const float* __restrict__ Wr, const float* __restrict__ br,
                                              const float* __restrict__ Whm2, const float* __restrict__ bhm2,
                                              float* __restrict__ out){
  int bx = blockIdx.x;
  int n = (bx & 7)*64 + (bx >> 3);
  if (n >= NPROP) return;
  int tid = threadIdx.x;
  __shared__ __align__(16) float qhL[128];
  __shared__ float sc[8*441];
  __shared__ int   kiL[441];
  __shared__ __align__(16) float ctxL[128];
  __shared__ float xL[128];
  __shared__ float hidL[256];
  __shared__ float sumsL[8];
  __shared__ float stat[2];
  __shared__ float dots[16];
  int sp = TOPS[n];
  int cls = TOPC[n];
  int orow = RANK[n];
  const int c128 = tid & 127, ks4 = (tid >> 7) * 32;    // 4-way split-k
  float qreg = 0.f;
  if (tid < 128){
    float qx = (float)(sp/132)+0.5f, qy = (float)(sp%132)+0.5f;
    ctxL[tid] = fmaxf(qx*pW1[tid] + qy*pW1[128+tid] + pb1[tid], 0.f);
    qreg = LFF[(size_t)sp*128+tid] + Wcls[tid*6+cls] + bcls[tid];
  }
  __syncthreads();
  {
    const float4* wp = (const float4*)(WP2T + (size_t)c128*128 + ks4);
    float pe = 0.f;
    #pragma unroll
    for (int k4=0;k4<8;++k4){
      float4 w = wp[k4]; int kb = ks4 + k4*4;
      pe += ctxL[kb]*w.x + ctxL[kb+1]*w.y + ctxL[kb+2]*w.z + ctxL[kb+3]*w.w;
    }
    sc[tid] = pe;
  }
  __syncthreads();
  if (tid < 128) xL[tid] = qreg + pb2[tid] + ((sc[tid] + sc[tid+128]) + (sc[tid+256] + sc[tid+384]));
  __syncthreads();
  {
    const float4* wp = (const float4*)(WQT + (size_t)c128*128 + ks4);
    float qh = 0.f;
    #pragma unroll
    for (int k4=0;k4<8;++k4){
      float4 w = wp[k4]; int kb = ks4 + k4*4;
      qh += xL[kb]*w.x + xL[kb+1]*w.y + xL[kb+2]*w.z + xL[kb+3]*w.w;
    }
    sc[tid] = qh;
  }
  __syncthreads();
  if (tid < 128) qhL[tid] = bq[tid] + ((sc[tid] + sc[tid+128]) + (sc[tid+256] + sc[tid+384]));
  __syncthreads();
  int spx = sp/192, spy = sp%132;       // faithful to ref's //X_GRID, %Y_GRID
  for (int l = tid; l < 441; l += 512){
    int a = l/21, bb = l%21;
    int kidx = (spx + a - 10)*192 + (spy + bb - 10);
    bool msk = (kidx < 0) || (kidx >= HW);
    int kc = imin(imax(kidx,0), HW-1);
    kiL[l] = kc;
    const float4* kk4 = (const float4*)(KK + (size_t)kc*128);
    const float4* qh4 = (const float4*)qhL;
    #pragma unroll
    for (int hh=0; hh<8; ++hh){
      float acc = 0.f;
      #pragma unroll
      for (int d4=0; d4<4; ++d4){
        float4 kv = kk4[hh*4+d4]; float4 qv = qh4[hh*4+d4];
        acc += kv.x*qv.x + kv.y*qv.y + kv.z*qv.z + kv.w*qv.w;
      }
      sc[hh*441+l] = msk ? -1e9f : acc*0.25f;
    }
  }
  __syncthreads();
  int wave = tid>>6, lane = tid&63;
  {
    int hh = wave;                      // one head per wave (8 waves)
    float mx = -3.0e38f;
    for (int l = lane; l < 441; l += 64) mx = fmaxf(mx, sc[hh*441+l]);
    #pragma unroll
    for (int off=32; off; off>>=1) mx = fmaxf(mx, __shfl_xor(mx, off));
    float sum = 0.f;
    for (int l = lane; l < 441; l += 64){
      float e = __expf(sc[hh*441+l] - mx);
      sc[hh*441+l] = e; sum += e;
    }
    #pragma unroll
    for (int off=32; off; off>>=1) sum += __shfl_xor(sum, off);
    if (lane==0) sumsL[hh] = sum;
  }
  __syncthreads();
  {
    int hh = wave;
    float a[16];
    #pragma unroll
    for (int d=0; d<16; ++d) a[d]=0.f;
    for (int l = lane; l < 441; l += 64){
      float w = sc[hh*441+l];
      const float4* vv4 = (const float4*)(VV + (size_t)kiL[l]*128 + hh*16);
      #pragma unroll
      for (int d4=0; d4<4; ++d4){
        float4 v = vv4[d4];
        a[d4*4+0]+=w*v.x; a[d4*4+1]+=w*v.y; a[d4*4+2]+=w*v.z; a[d4*4+3]+=w*v.w;
      }
    }
    #pragma unroll
    for (int d=0; d<16; ++d){
      #pragma unroll
      for (int off=32; off; off>>=1) a[d] += __shfl_xor(a[d], off);
    }
    if (lane==0){
      float inv = 1.f/sumsL[hh];
      #pragma unroll
      for (int d=0; d<16; ++d) ctxL[hh*16+d] = a[d]*inv;
    }
  }
  __syncthreads();
  {
    const float4* wp = (const float4*)(WOT + (size_t)c128*128 + ks4);
    float acc = 0.f;
    #pragma unroll
    for (int k4=0;k4<8;++k4){
      float4 w = wp[k4]; int kb = ks4 + k4*4;
      acc += ctxL[kb]*w.x + ctxL[kb+1]*w.y + ctxL[kb+2]*w.z + ctxL[kb+3]*w.w;
    }
    sc[tid] = acc;
  }
  __syncthreads();
  float x1v = 0.f;
  if (tid < 128){
    x1v = qreg + bo[tid] + ((sc[tid] + sc[tid+128]) + (sc[tid+256] + sc[tid+384]));
    xL[tid] = x1v;
  }
  __syncthreads();
  if (tid < 64){
    float u0 = xL[tid], u1 = xL[tid+64];
    float s = u0+u1, s2 = u0*u0+u1*u1;
    #pragma unroll
    for (int off=32; off; off>>=1){ s += __shfl_xor(s, off); s2 += __shfl_xor(s2, off); }
    if (tid==0){ float mean = s*(1.f/128.f); float var = s2*(1.f/128.f) - mean*mean;
      stat[0]=mean; stat[1]=rsqrtf(var + 1e-5f); }
  }
  __syncthreads();
  if (tid < 128) xL[tid] = (x1v - stat[0])*stat[1]*g1[tid] + b1[tid];
  __syncthreads();
  {
    int o = tid & 255, half = tid >> 8;   // 2-way split-k over 128
    const float4* wp = (const float4*)(WF1T + (size_t)o*128 + half*64);
    float hv = 0.f;
    #pragma unroll
    for (int k4=0;k4<16;++k4){
      float4 w = wp[k4]; int kb = half*64 + k4*4;
      hv += xL[kb]*w.x + xL[kb+1]*w.y + xL[kb+2]*w.z + xL[kb+3]*w.w;
    }
    sc[tid] = hv;
  }
  __syncthreads();
  if (tid < 256) hidL[tid] = fmaxf(bf1[tid] + sc[tid] + sc[tid+256], 0.f);
  __syncthreads();
  {
    int q = tid >> 7;                     // 4-way split-k over 256
    const float4* wp = (const float4*)(WF2T + (size_t)c128*256 + q*64);
    float acc = 0.f;
    #pragma unroll
    for (int k4=0;k4<16;++k4){
      float4 w = wp[k4]; int kb = q*64 + k4*4;
      acc += hidL[kb]*w.x + hidL[kb+1]*w.y + hidL[kb+2]*w.z + hidL[kb+3]*w.w;
    }
    sc[tid] = acc;
  }
  __syncthreads();
  float x2v = 0.f;
  if (tid < 128) x2v = xL[tid] + bf2[tid] + ((sc[tid] + sc[tid+128]) + (sc[tid+256] + sc[tid+384]));
  __syncthreads();
  if (tid < 128) hidL[tid] = x2v;
  __syncthreads();
  if (tid < 64){
    float u0 = hidL[tid], u1 = hidL[tid+64];
    float s = u0+u1, s2 = u0*u0+u1*u1;
    #pragma unroll
    for (int off=32; off; off>>=1){ s += __shfl_xor(s, off); s2 += __shfl_xor(s2, off); }
    if (tid==0){ float mean = s*(1.f/128.f); float var = s2*(1.f/128.f) - mean*mean;
      stat[0]=mean; stat[1]=rsqrtf(var + 1e-5f); }
  }
  __syncthreads();
  if (tid < 128) xL[tid] = (x2v - stat[0])*stat[1]*g2[tid] + b2[tid];   // final x2
  __syncthreads();
  if (tid < 14){
    const float* Wp; float bb;
    if (tid < 2)      { Wp = Wc + tid*128;        bb = bc[tid];      }
    else if (tid < 3) { Wp = Wh;                  bb = bh[0];        }
    else if (tid < 6) { Wp = Wd + (tid-3)*128;    bb = bd[tid-3];    }
    else if (tid < 8) { Wp = Wr + (tid-6)*128;    bb = br[tid-6];    }
    else              { Wp = Whm2 + (tid-8)*128;  bb = bhm2[tid-8];  }
    float acc = bb;
    for (int k=0;k<128;++k) acc += xL[k]*Wp[k];
    dots[tid] = acc;
  }
  __syncthreads();
  if (tid == 0){
    float qpx = (float)(sp/132)+0.5f, qpy = (float)(sp%132)+0.5f;
    float cx = (dots[0]+qpx)*0.64f - 61.44f;
    float cy = (dots[1]+qpy)*0.64f - 42.24f;
    float e0 = expf(dots[3]), e1 = expf(dots[4]), e2 = expf(dots[5]);
    float hgt = dots[2] - e2*0.5f;
    float rot = atanf(dots[6]/(dots[7] + 1e-6f));
    float bestv = -1.f; int bestc = 0;
    #pragma unroll
    for (int m=0;m<6;++m){
      float s = 1.f/(1.f + expf(-dots[8+m]));
      if (s > bestv){ bestv = s; bestc = m; }
    }
    float* o = out + (size_t)orow*9;
    o[0]=cx; o[1]=cy; o[2]=hgt; o[3]=e0; o[4]=e1; o[5]=e2; o[6]=rot;
    o[7]=(float)bestc; o[8]=bestv;
  }
}

// ---------------- launcher ----------------
extern "C" void kernel_launch(void* const* d_in, const int* in_sizes, int n_in,
                              void* d_out, int out_size, void* d_ws, size_t ws_size,
                              hipStream_t stream){
  (void)in_sizes; (void)n_in; (void)out_size;
  const float* IN   = (const float*)d_in[0];
  const float* Wsh  = (const float*)d_in[1];
  const float* bsh  = (const float*)d_in[2];
  const float* Whm  = (const float*)d_in[3];
  const float* bhm  = (const float*)d_in[4];
  const float* Wcls = (const float*)d_in[5];
  const float* bcls = (const float*)d_in[6];
  const float* Wp1  = (const float*)d_in[7];
  const float* bp1  = (const float*)d_in[8];
  const float* Wp2  = (const float*)d_in[9];
  const float* bp2  = (const float*)d_in[10];
  const float* Wq   = (const float*)d_in[11];
  const float* bq   = (const float*)d_in[12];
  const float* Wk   = (const float*)d_in[13];
  const float* bk   = (const float*)d_in[14];
  const float* Wv   = (const float*)d_in[15];
  const float* bv   = (const float*)d_in[16];
  const float* Wo   = (const float*)d_in[17];
  const float* bo   = (const float*)d_in[18];
  const float* g1   = (const float*)d_in[19];
  const float* b1   = (const float*)d_in[20];
  const float* g2   = (const float*)d_in[21];
  const float* b2   = (const float*)d_in[22];
  const float* Wf1  = (const float*)d_in[23];
  const float* bf1  = (const float*)d_in[24];
  const float* Wf2  = (const float*)d_in[25];
  const float* bf2  = (const float*)d_in[26];
  const float* Wc   = (const float*)d_in[27];
  const float* bc   = (const float*)d_in[28];
  const float* Wh   = (const float*)d_in[29];
  const float* bh   = (const float*)d_in[30];
  const float* Wd   = (const float*)d_in[31];
  const float* bd   = (const float*)d_in[32];
  const float* Wr   = (const float*)d_in[33];
  const float* br   = (const float*)d_in[34];
  const float* Whm2 = (const float*)d_in[37];
  const float* bhm2 = (const float*)d_in[38];
  float* out = (float*)d_out;
  float* W = (float*)d_ws;

  const size_t N_LFF  = (size_t)HW*128;
  const size_t OFF_LFF  = 0;
  const size_t OFF_KK   = OFF_LFF + N_LFF;         // conv1 partial P0, then KK
  const size_t OFF_VV   = OFF_KK + N_LFF;          // conv1 partial P1, then VV
  const size_t OFF_W6   = OFF_VV + N_LFF;          // 6912
  const size_t OFF_HMS  = OFF_W6 + 6912;           // 152064
  const size_t OFF_VALS = OFF_HMS + 152064;        // 152064
  const size_t OFF_HIST = OFF_VALS + 152064;       // 65536
  const size_t OFF_SCAN = OFF_HIST + 65536;        // 16
  const size_t OFF_CNT  = OFF_SCAN + 16;           // 16
  const size_t OFF_CV   = OFF_CNT + 16;            // CAP
  const size_t OFF_CI   = OFF_CV + CAP;            // CAP
  const size_t OFF_TOPS = OFF_CI + CAP;            // 512
  const size_t OFF_TOPC = OFF_TOPS + 512;          // 512
  const size_t OFF_RANK = OFF_TOPC + 512;          // 512
  const size_t OFF_WQT  = OFF_RANK + 512;          // 16384
  const size_t OFF_WP2T = OFF_WQT + 16384;         // 16384
  const size_t OFF_WOT  = OFF_WP2T + 16384;        // 16384
  const size_t OFF_WF1T = OFF_WOT + 16384;         // 32768
  const size_t OFF_WF2T = OFF_WF1T + 32768;        // 32768
  const size_t OFF_BQ0  = OFF_WF2T + 32768;        // 184320 floats (= 368640 bf16)
  const size_t OFF_BQ1  = OFF_BQ0 + 184320;
  const size_t OFF_BQ2  = OFF_BQ1 + 184320;
  const size_t TOTAL    = OFF_BQ2 + 184320;
  if (ws_size < TOTAL*sizeof(float)) return;

  ushort_t* BQ0 = (ushort_t*)(W + OFF_BQ0);
  ushort_t* BQ1 = (ushort_t*)(W + OFF_BQ1);
  ushort_t* BQ2 = (ushort_t*)(W + OFF_BQ2);

  // k_wt also zeroes HIST|SCAN|CNT (65568 ints, contiguous at OFF_HIST)
  k_wt    <<<1152, 256, 0, stream>>>(Wsh, Whm, Wq, Wp2, Wo, Wf1, Wf2,
                                     W+OFF_W6,
                                     W+OFF_WQT, W+OFF_WP2T, W+OFF_WOT, W+OFF_WF1T, W+OFF_WF2T,
                                     BQ0, BQ1, BQ2,
                                     (int*)(W+OFF_HIST));
  k_conv1 <<<dim3(396,2), 256, 0, stream>>>(IN, BQ0, BQ1, BQ2, W+OFF_KK, W+OFF_VV);
  k_cadd2 <<<3168, 256, 0, stream>>>(W+OFF_LFF, W+OFF_KK, W+OFF_VV, bsh);
  k_mid   <<<1188, 256, 0, stream>>>(W+OFF_LFF, Wp1, bp1, Wp2, bp2, Wk, bk, Wv, bv,
                                     W+OFF_KK, W+OFF_VV, W+OFF_W6, bhm, W+OFF_HMS);
  k_nms   <<<594,  256, 0, stream>>>(W+OFF_HMS, W+OFF_VALS, (int*)(W+OFF_HIST));
  k_scan  <<<1,   1024, 0, stream>>>((const int*)(W+OFF_HIST), (int*)(W+OFF_SCAN));
  k_collect<<<594, 256, 0, stream>>>(W+OFF_VALS, (const int*)(W+OFF_SCAN),
                                     (int*)(W+OFF_CNT), W+OFF_CV, (int*)(W+OFF_CI));
  k_sort  <<<1,   1024, 0, stream>>>(W+OFF_CV, (const int*)(W+OFF_CI), (const int*)(W+OFF_CNT),
                                     (int*)(W+OFF_TOPS), (int*)(W+OFF_TOPC), (int*)(W+OFF_RANK));
  k_attn  <<<512,  512, 0, stream>>>(W+OFF_KK, W+OFF_VV, W+OFF_LFF,
                                     (const int*)(W+OFF_TOPS), (const int*)(W+OFF_TOPC),
                                     (const int*)(W+OFF_RANK),
                                     Wcls, bcls, Wp1, bp1, W+OFF_WP2T, bp2, W+OFF_WQT, bq,
                                     W+OFF_WOT, bo, g1, b1, W+OFF_WF1T, bf1, W+OFF_WF2T, bf2, g2, b2,
                                     Wc, bc, Wh, bh, Wd, bd, Wr, br, Whm2, bhm2, out);
}

// Round 16
// 544.438 us; speedup vs baseline: 1.0860x; 1.0087x over previous
//
#include <hip/hip_runtime.h>
#include <math.h>
#include <float.h>

#define XG 192
#define YG 132
#define HW 25344           // 192*132
#define NCLS 6
#define NPROP 500
#define LWIN 441
#define CAP 2048           // candidate cap for top-k sort (one-level select)

typedef unsigned short ushort_t;
typedef __attribute__((ext_vector_type(8))) short bf8v;   // 8 bf16 (4 VGPRs)
typedef __attribute__((ext_vector_type(4))) float f4v;    // 4 fp32 acc

static __device__ __forceinline__ int imin(int a,int b){return a<b?a:b;}
static __device__ __forceinline__ int imax(int a,int b){return a>b?a:b;}

// async global->LDS, 16B per lane; LDS dest is wave-uniform base + lane*16
__device__ __forceinline__ void gl_lds16(const float* gp, float* lp){
  __builtin_amdgcn_global_load_lds(
      (const __attribute__((address_space(1))) unsigned int*)gp,
      (__attribute__((address_space(3))) unsigned int*)lp,
      16, 0, 0);
}
__device__ __forceinline__ void gl_lds16u(const ushort_t* gp, ushort_t* lp){
  __builtin_amdgcn_global_load_lds(
      (const __attribute__((address_space(1))) unsigned int*)gp,
      (__attribute__((address_space(3))) unsigned int*)lp,
      16, 0, 0);
}

__device__ __forceinline__ ushort_t f2bf(float x){          // RNE truncate to bf16
  unsigned u = __float_as_uint(x);
  return (ushort_t)((u + 0x7FFFu + ((u>>16)&1u)) >> 16);
}
__device__ __forceinline__ float bf2f(ushort_t h){
  return __uint_as_float(((unsigned)h)<<16);
}

// ---------------- weight prep: bf16-split conv1 weights + W6 + attn transposes + zeroing ----------
// BQs[(tap*8+chunk)*5120 + n*40 + kl] = split_s( Ws[n][chunk*32+kl][tap] ), kl<32; 32..39 pad unused
__global__ __launch_bounds__(256) void k_wt(const float* __restrict__ Ws,
                                            const float* __restrict__ Whm,
                                            const float* __restrict__ Wq,
                                            const float* __restrict__ Wp2,
                                            const float* __restrict__ Wo,
                                            const float* __restrict__ Wf1,
                                            const float* __restrict__ Wf2,
                                            float* __restrict__ W6,
                                            float* __restrict__ WQT,
                                            float* __restrict__ WP2T,
                                            float* __restrict__ WOT,
                                            float* __restrict__ WF1T,
                                            float* __restrict__ WF2T,
                                            ushort_t* __restrict__ BQ0,
                                            ushort_t* __restrict__ BQ1,
                                            ushort_t* __restrict__ BQ2,
                                            int* __restrict__ Z){
  int t = blockIdx.x*256 + threadIdx.x;
  if (t < 294912){
    int kl = t & 31;
    int rest = t >> 5;
    int n = rest & 127;
    int tc = rest >> 7;            // tap*8 + chunk
    int tap = tc >> 3, chunk = tc & 7;
    int c = chunk*32 + kl;
    float v = Ws[(size_t)n*2304 + c*9 + tap];
    ushort_t h0 = f2bf(v);
    float r1 = v - bf2f(h0);
    ushort_t h1 = f2bf(r1);
    float r2 = r1 - bf2f(h1);
    ushort_t h2 = f2bf(r2);
    size_t dst = (size_t)tc*5120 + n*40 + kl;
    BQ0[dst] = h0; BQ1[dst] = h1; BQ2[dst] = h2;
  }
  if (t < 6912){
    int c = t & 127, row = t >> 7;      // row = cls*9+tap, 54 rows
    int cls = row / 9, tap = row % 9;
    W6[t] = Whm[(size_t)cls*1152 + c*9 + tap];
  }
  if (t < 16384){
    int k = t & 127, c = t >> 7;
    WQT[t]  = Wq [(size_t)k*128 + c];
    WP2T[t] = Wp2[(size_t)k*128 + c];
    WOT[t]  = Wo [(size_t)k*128 + c];
  }
  if (t < 32768){
    { int k = t & 127, o = t >> 7;  WF1T[t] = Wf1[(size_t)k*256 + o]; }
    { int k = t & 255, c = t >> 8;  WF2T[t] = Wf2[(size_t)k*128 + c]; }
  }
  if (t < 65568) Z[t] = 0;              // HIST 65536 | SCAN 16 | CNT 16
}

// ---------------- conv1 v11 (R13-proven 170us best): split-bf16 MFMA, K-split x2, M=64 ----------
// grid (396, 2): 396 = 3 i-strips(64) x 132 cols; blockIdx.y = 128-ch half (chunks g*4..g*4+3).
// block 256 = 4 waves. M=64, N=128; per k-step one 16x16x32 MFMA-K, 6 split terms.
// Raw fp32 partials -> P[g]; k_cadd2 combines with bias+relu.
// Frozen: R14 (M=96/65KB LDS) and R12 (single launch, 396 blocks) both measured worse.
__global__ __launch_bounds__(256, 3) void k_conv1(const float* __restrict__ IN,
                                                  const ushort_t* __restrict__ BQ0,
                                                  const ushort_t* __restrict__ BQ1,
                                                  const ushort_t* __restrict__ BQ2,
                                                  float* __restrict__ P0,
                                                  float* __restrict__ P1){
  const int b  = blockIdx.x;
  const int g  = blockIdx.y;
  const int i0 = (b % 3) * 64;
  const int j  = b / 3;
  const int tid = threadIdx.x;
  const int w    = tid >> 6;
  const int lane = tid & 63;
  const int l15  = lane & 15, quad = lane >> 4;
  __shared__ __align__(16) ushort_t SM[23280];   // A: 3x2640 | B: 3x5120 (46560 B)
  ushort_t* As0 = SM;                 // [px 66][chpad 40]
  ushort_t* As1 = SM + 2640;
  ushort_t* As2 = SM + 5280;
  ushort_t* Bs0 = SM + 7920;          // [n 128][chpad 40]
  ushort_t* Bs1 = SM + 13040;
  ushort_t* Bs2 = SM + 18160;
  f4v acc[4][2];
  #pragma unroll
  for (int mq=0;mq<4;++mq)
    #pragma unroll
    for (int nt=0;nt<2;++nt) acc[mq][nt] = (f4v){0.f,0.f,0.f,0.f};

  for (int cq=0; cq<4; ++cq){
    const int chunk = g*4 + cq;
    for (int kw=0; kw<3; ++kw){
      __syncthreads();                 // prior tap's reads of As/Bs done
      {
        int gj = j - 1 + kw;
        bool jok = (unsigned)gj < 132u;
        for (int e = tid; e < 2112; e += 256){
          int c = e / 66, ii = e - c*66;
          int gi = i0 - 1 + ii;
          float v = 0.f;
          if (jok && (unsigned)gi < 192u)
            v = IN[(size_t)(chunk*32 + c)*25344 + gj*192 + gi];
          ushort_t h0 = f2bf(v);
          float r1 = v - bf2f(h0);
          ushort_t h1 = f2bf(r1);
          float r2 = r1 - bf2f(h1);
          ushort_t h2 = f2bf(r2);
          int a = ii*40 + c;
          As0[a] = h0; As1[a] = h1; As2[a] = h2;
        }
      }
      for (int kh=0; kh<3; ++kh){
        if (kh > 0) __syncthreads();   // prior mfma's Bs reads done
        {
          int tc = (kh*3 + kw)*8 + chunk;
          const ushort_t* s0 = BQ0 + (size_t)tc*5120;
          const ushort_t* s1 = BQ1 + (size_t)tc*5120;
          const ushort_t* s2 = BQ2 + (size_t)tc*5120;
          gl_lds16u(s0 + (size_t)tid*8,       Bs0 + (size_t)(w*64)*8);
          gl_lds16u(s0 + (size_t)(256+tid)*8, Bs0 + (size_t)(256 + w*64)*8);
          gl_lds16u(s1 + (size_t)tid*8,       Bs1 + (size_t)(w*64)*8);
          gl_lds16u(s1 + (size_t)(256+tid)*8, Bs1 + (size_t)(256 + w*64)*8);
          gl_lds16u(s2 + (size_t)tid*8,       Bs2 + (size_t)(w*64)*8);
          gl_lds16u(s2 + (size_t)(256+tid)*8, Bs2 + (size_t)(256 + w*64)*8);
          if (tid < 128){
            gl_lds16u(s0 + (size_t)(512+tid)*8, Bs0 + (size_t)(512 + w*64)*8);
            gl_lds16u(s1 + (size_t)(512+tid)*8, Bs1 + (size_t)(512 + w*64)*8);
            gl_lds16u(s2 + (size_t)(512+tid)*8, Bs2 + (size_t)(512 + w*64)*8);
          }
        }
        __syncthreads();               // staging visible (A for kh==0, B always)
        bf8v A0[4], A1[4], A2[4];
        #pragma unroll
        for (int mq=0; mq<4; ++mq){
          int off = (mq*16 + l15 + kh)*40 + quad*8;
          A0[mq] = *(const bf8v*)&As0[off];
          A1[mq] = *(const bf8v*)&As1[off];
          A2[mq] = *(const bf8v*)&As2[off];
        }
        bf8v B0[2], B1[2], B2[2];
        #pragma unroll
        for (int ntl=0; ntl<2; ++ntl){
          int off = ((w*2+ntl)*16 + l15)*40 + quad*8;
          B0[ntl] = *(const bf8v*)&Bs0[off];
          B1[ntl] = *(const bf8v*)&Bs1[off];
          B2[ntl] = *(const bf8v*)&Bs2[off];
        }
        #pragma unroll
        for (int mq=0;mq<4;++mq){
          #pragma unroll
          for (int ntl=0;ntl<2;++ntl){
            f4v c = acc[mq][ntl];
            c = __builtin_amdgcn_mfma_f32_16x16x32_bf16(A0[mq], B0[ntl], c, 0,0,0);
            c = __builtin_amdgcn_mfma_f32_16x16x32_bf16(A0[mq], B1[ntl], c, 0,0,0);
            c = __builtin_amdgcn_mfma_f32_16x16x32_bf16(A1[mq], B0[ntl], c, 0,0,0);
            c = __builtin_amdgcn_mfma_f32_16x16x32_bf16(A0[mq], B2[ntl], c, 0,0,0);
            c = __builtin_amdgcn_mfma_f32_16x16x32_bf16(A1[mq], B1[ntl], c, 0,0,0);
            c = __builtin_amdgcn_mfma_f32_16x16x32_bf16(A2[mq], B0[ntl], c, 0,0,0);
            acc[mq][ntl] = c;
          }
        }
      }
    }
  }
  __syncthreads();
  float* Cs = (float*)SM;              // 64 x 128 fp32 = 32768 B <= 46560
  #pragma unroll
  for (int mq=0;mq<4;++mq)
    #pragma unroll
    for (int ntl=0;ntl<2;++ntl)
      #pragma unroll
      for (int r=0;r<4;++r){
        int m = mq*16 + quad*4 + r;          // C/D: row = quad*4+reg
        int oc = (w*2+ntl)*16 + l15;         //      col = lane&15
        Cs[m*128 + oc] = acc[mq][ntl][r];
      }
  __syncthreads();
  float* dst = g ? P1 : P0;
  for (int e = tid; e < 2048; e += 256){
    int m = e >> 5, ocq = e & 31;
    float4 v = *(float4*)&Cs[m*128 + ocq*4];
    int p = (i0 + m)*132 + j;
    *(float4*)&dst[(size_t)p*128 + ocq*4] = v;
  }
}

// ---------------- combine 2 k-split partials + bias + relu ----------------
__global__ __launch_bounds__(256) void k_cadd2(float* __restrict__ LFF,
                                               const float* __restrict__ P0,
                                               const float* __restrict__ P1,
                                               const float* __restrict__ bias){
  int t = blockIdx.x*256 + threadIdx.x;   // 3168*256 = 811008 float4s
  float4 a = ((const float4*)P0)[t];
  float4 b = ((const float4*)P1)[t];
  float4 bs = ((const float4*)bias)[t & 31];
  float4 r;
  r.x = fmaxf(a.x+b.x+bs.x, 0.f);
  r.y = fmaxf(a.y+b.y+bs.y, 0.f);
  r.z = fmaxf(a.z+b.z+bs.z, 0.f);
  r.w = fmaxf(a.w+b.w+bs.w, 0.f);
  ((float4*)LFF)[t] = r;
}

// ---------------- fused (kkvv | conv2) ; both weight paths LDS-staged (R10/R11-proven) ----------
__global__ __launch_bounds__(256) void k_mid(const float* __restrict__ LFF,
                                             const float* __restrict__ W1, const float* __restrict__ b1,
                                             const float* __restrict__ W2, const float* __restrict__ b2,
                                             const float* __restrict__ Wk, const float* __restrict__ bk,
                                             const float* __restrict__ Wv, const float* __restrict__ bv,
                                             float* __restrict__ KK, float* __restrict__ VV,
                                             const float* __restrict__ W6, const float* __restrict__ bhm,
                                             float* __restrict__ HMS){
  __shared__ float smem[12288];   // kkvv: hs 4096 | sf 4096 | wbuf 4096 (48KB)
  const int tid = threadIdx.x;
  const int wv4 = tid >> 6;
  if (blockIdx.x < 792){
    float* hs   = smem;
    float* sf   = smem + 4096;
    float* wbuf = smem + 8192;
    const int p0 = blockIdx.x*32;
    for (int e=tid; e<4096; e+=256){
      int k = e>>5, px = e&31;
      int p = p0+px;
      float bx = (float)(p/132)+0.5f, by = (float)(p%132)+0.5f;
      hs[k*32+px] = fmaxf(bx*W1[k] + by*W1[128+k] + b1[k], 0.f);
    }
    for (int e=tid; e<4096; e+=256){
      int px = e>>7, k = e&127;
      sf[k*32+px] = LFF[(size_t)(p0+px)*128 + k];
    }
    const int pxg = tid & 15, ocg = tid >> 4;   // 16 x 16
    const int px0 = pxg*2, oc0 = ocg*8;
    float accA[2][8];
    #pragma unroll
    for (int r=0;r<2;++r)
      #pragma unroll
      for (int u=0;u<8;++u) accA[r][u]=0.f;
    for (int c0=0; c0<128; c0+=32){
      __syncthreads();
      const float* wsrc = W2 + (size_t)c0*128;
      #pragma unroll
      for (int r=0;r<4;++r)
        gl_lds16(wsrc + (size_t)(r*256+tid)*4, wbuf + (size_t)(r*256+wv4*64)*4);
      __syncthreads();
      #pragma unroll 2
      for (int k=0;k<32;++k){
        float a0 = hs[(c0+k)*32+px0], a1 = hs[(c0+k)*32+px0+1];
        const float4* w = (const float4*)(wbuf + (size_t)k*128 + oc0);
        float4 w0 = w[0], w1 = w[1];
        accA[0][0]+=a0*w0.x; accA[0][1]+=a0*w0.y; accA[0][2]+=a0*w0.z; accA[0][3]+=a0*w0.w;
        accA[0][4]+=a0*w1.x; accA[0][5]+=a0*w1.y; accA[0][6]+=a0*w1.z; accA[0][7]+=a0*w1.w;
        accA[1][0]+=a1*w0.x; accA[1][1]+=a1*w0.y; accA[1][2]+=a1*w0.z; accA[1][3]+=a1*w0.w;
        accA[1][4]+=a1*w1.x; accA[1][5]+=a1*w1.y; accA[1][6]+=a1*w1.z; accA[1][7]+=a1*w1.w;
      }
    }
    __syncthreads();
    #pragma unroll
    for (int u=0;u<8;++u){
      float bb = b2[oc0+u];
      hs[(oc0+u)*32+px0]   = sf[(oc0+u)*32+px0]   + accA[0][u] + bb;
      hs[(oc0+u)*32+px0+1] = sf[(oc0+u)*32+px0+1] + accA[1][u] + bb;
    }
    float accK[2][8], accV[2][8];
    #pragma unroll
    for (int u=0;u<8;++u){
      float k0 = bk[oc0+u], v0 = bv[oc0+u];
      accK[0][u]=k0; accK[1][u]=k0; accV[0][u]=v0; accV[1][u]=v0;
    }
    for (int c0=0; c0<128; c0+=16){
      __syncthreads();
      #pragma unroll
      for (int r=0;r<2;++r){
        gl_lds16(Wk + (size_t)c0*128 + (size_t)(r*256+tid)*4, wbuf + (size_t)(r*256+wv4*64)*4);
        gl_lds16(Wv + (size_t)c0*128 + (size_t)(r*256+tid)*4, wbuf + 2048 + (size_t)(r*256+wv4*64)*4);
      }
      __syncthreads();
      #pragma unroll 2
      for (int k=0;k<16;++k){
        int kk = c0+k;
        float s0 = hs[kk*32+px0], s1 = hs[kk*32+px0+1];
        float f0 = sf[kk*32+px0], f1 = sf[kk*32+px0+1];
        const float4* wkp = (const float4*)(wbuf + (size_t)k*128 + oc0);
        const float4* wvp = (const float4*)(wbuf + 2048 + (size_t)k*128 + oc0);
        float4 k0v = wkp[0], k1v = wkp[1], v0v = wvp[0], v1v = wvp[1];
        accK[0][0]+=s0*k0v.x; accK[0][1]+=s0*k0v.y; accK[0][2]+=s0*k0v.z; accK[0][3]+=s0*k0v.w;
        accK[0][4]+=s0*k1v.x; accK[0][5]+=s0*k1v.y; accK[0][6]+=s0*k1v.z; accK[0][7]+=s0*k1v.w;
        accK[1][0]+=s1*k0v.x; accK[1][1]+=s1*k0v.y; accK[1][2]+=s1*k0v.z; accK[1][3]+=s1*k0v.w;
        accK[1][4]+=s1*k1v.x; accK[1][5]+=s1*k1v.y; accK[1][6]+=s1*k1v.z; accK[1][7]+=s1*k1v.w;
        accV[0][0]+=f0*v0v.x; accV[0][1]+=f0*v0v.y; accV[0][2]+=f0*v0v.z; accV[0][3]+=f0*v0v.w;
        accV[0][4]+=f0*v1v.x; accV[0][5]+=f0*v1v.y; accV[0][6]+=f0*v1v.z; accV[0][7]+=f0*v1v.w;
        accV[1][0]+=f1*v0v.x; accV[1][1]+=f1*v0v.y; accV[1][2]+=f1*v0v.z; accV[1][3]+=f1*v0v.w;
        accV[1][4]+=f1*v1v.x; accV[1][5]+=f1*v1v.y; accV[1][6]+=f1*v1v.z; accV[1][7]+=f1*v1v.w;
      }
    }
    #pragma unroll
    for (int r=0;r<2;++r){
      int p = p0+px0+r;
      float4* oK = (float4*)(KK + (size_t)p*128 + oc0);
      float4* oV = (float4*)(VV + (size_t)p*128 + oc0);
      float4 t0, t1;
      t0.x=accK[r][0]; t0.y=accK[r][1]; t0.z=accK[r][2]; t0.w=accK[r][3];
      t1.x=accK[r][4]; t1.y=accK[r][5]; t1.z=accK[r][6]; t1.w=accK[r][7];
      oK[0]=t0; oK[1]=t1;
      t0.x=accV[r][0]; t0.y=accV[r][1]; t0.z=accV[r][2]; t0.w=accV[r][3];
      t1.x=accV[r][4]; t1.y=accV[r][5]; t1.z=accV[r][6]; t1.w=accV[r][7];
      oV[0]=t0; oV[1]=t1;
    }
  } else {
    float* w6s = smem;          // 6912 floats
    float* red = smem + 8192;
    for (int e=tid; e<6912; e+=256) w6s[e] = W6[e];
    __syncthreads();
    int lane = tid & 63, wave = tid >> 6;
    int p = (blockIdx.x - 792)*64 + lane;        // 396*64 = 25344
    int i = p/132, j = p%132;
    float acc[6] = {0.f,0.f,0.f,0.f,0.f,0.f};
    int cbase = wave*32;
    #pragma unroll
    for (int kh=0; kh<3; ++kh){
      int gi = i+kh-1;
      if ((unsigned)gi >= 192u) continue;
      #pragma unroll
      for (int kw=0; kw<3; ++kw){
        int gj = j+kw-1;
        if ((unsigned)gj >= 132u) continue;
        const float* row = LFF + (size_t)(gi*132+gj)*128 + cbase;
        int tap = kh*3+kw;
        #pragma unroll
        for (int cq=0; cq<8; ++cq){
          float4 v = *(const float4*)(row + cq*4);
          #pragma unroll
          for (int cls=0; cls<6; ++cls){
            float4 wv = *(const float4*)(w6s + (size_t)(cls*9+tap)*128 + cbase + cq*4);
            acc[cls] += v.x*wv.x + v.y*wv.y + v.z*wv.z + v.w*wv.w;
          }
        }
      }
    }
    __syncthreads();
    #pragma unroll
    for (int c=0;c<6;++c) red[(wave*6+c)*64 + lane] = acc[c];
    __syncthreads();
    if (wave==0){
      #pragma unroll
      for (int c=0;c<6;++c){
        float s = red[c*64+lane] + red[(6+c)*64+lane] + red[(12+c)*64+lane] + red[(18+c)*64+lane] + bhm[c];
        HMS[(size_t)c*HW + p] = 1.f/(1.f+expf(-s));
      }
    }
  }
}

// ---------------- NMS + threshold + 16-bit histogram ----------------
__global__ __launch_bounds__(256) void k_nms(const float* __restrict__ HMS,
                                             float* __restrict__ VALS,
                                             int* __restrict__ HIST){
  int t = blockIdx.x*256 + threadIdx.x;   // 594*256 = 152064
  int c = t / HW, p = t % HW;
  int i = p/132, j = p%132;
  float h = HMS[t];
  float v;
  if (c < 3){
    v = 0.f;
    if (i>=1 && i<=190 && j>=1 && j<=130){
      float m = -1e30f;
      #pragma unroll
      for (int di=-1;di<=1;++di)
        #pragma unroll
        for (int dj=-1;dj<=1;++dj)
          m = fmaxf(m, HMS[(size_t)c*HW + (i+di)*132 + (j+dj)]);
      if (h == m) v = h;
    }
  } else v = h;
  if (!(v > 0.01f)) v = 0.f;
  VALS[t] = v;
  if (v > 0.f) atomicAdd(HIST + (__float_as_uint(v)>>16), 1);
}

// ---------------- level-1 scan: parallel suffix scan (R9-proven) ----------------
__global__ __launch_bounds__(1024) void k_scan(const int* __restrict__ HIST, int* __restrict__ SCAN){
  __shared__ int part[1024];
  __shared__ int gsel;
  int t = threadIdx.x;
  int s = 0, base = t*64;
  for (int u=0;u<64;++u) s += HIST[base+u];
  part[t] = s;
  __syncthreads();
  for (int off=1; off<1024; off<<=1){
    int add = (t+off < 1024) ? part[t+off] : 0;
    __syncthreads();
    part[t] += add;
    __syncthreads();
  }
  int total = part[0];
  int mineI = part[t];
  int nextI = (t < 1023) ? part[t+1] : 0;
  if (mineI >= NPROP && nextI < NPROP) gsel = t;
  if (t == 0 && total < NPROP) gsel = -1;
  __syncthreads();
  int g = gsel;
  if (g < 0){
    if (t==0){ SCAN[0] = 0; SCAN[1] = total; }
    return;
  }
  int cumG = (g < 1023) ? part[g+1] : 0;
  if (t < 64){
    int x = HIST[g*64 + t];
    #pragma unroll
    for (int off=1; off<64; off<<=1){
      int y = __shfl_down(x, off);
      x += (t + off < 64) ? y : 0;
    }
    int Snext = __shfl_down(x, 1);
    int incl  = cumG + x;
    int nextc = (t==63) ? cumG : cumG + Snext;
    if (incl >= NPROP && nextc < NPROP){
      SCAN[0] = g*64 + t;
      SCAN[1] = nextc;
    }
  }
}

// ---------------- collect candidates with bin >= bstar ----------------
__global__ __launch_bounds__(256) void k_collect(const float* __restrict__ VALS,
                                                 const int* __restrict__ SCAN,
                                                 int* __restrict__ CNT,
                                                 float* __restrict__ CV, int* __restrict__ CI){
  int t = blockIdx.x*256 + threadIdx.x;   // 594*256 = 152064
  float v = VALS[t];
  int bstar = SCAN[0];
  if (v > 0.f && (int)(__float_as_uint(v)>>16) >= bstar){
    int pos = atomicAdd(CNT, 1);
    if (pos < CAP){ CV[pos] = v; CI[pos] = t; }
  }
}

// ---------------- bitonic sort candidates (2048), take top-500 ----------------
__global__ __launch_bounds__(1024) void k_sort(const float* __restrict__ CV, const int* __restrict__ CI,
                                               const int* __restrict__ CNT,
                                               int* __restrict__ TOPS, int* __restrict__ TOPC){
  __shared__ float sv[CAP];
  __shared__ int   si[CAP];
  int tid = threadIdx.x;
  int M = imin(CNT[0], CAP);
  for (int i=tid; i<CAP; i+=1024){
    if (i < M){ sv[i] = CV[i]; si[i] = CI[i]; }
    else      { sv[i] = -1.f;  si[i] = 0x7fffffff; }
  }
  __syncthreads();
  for (int k=2; k<=CAP; k<<=1){
    for (int j=k>>1; j>0; j>>=1){
      for (int i=tid; i<CAP; i+=1024){
        int p = i ^ j;
        if (p > i){
          bool up = ((i & k) == 0);
          float va = sv[i], vb = sv[p];
          int ia = si[i], ib = si[p];
          bool aFirst = (va > vb) || (va == vb && ia < ib);
          bool bFirst = (vb > va) || (vb == va && ib < ia);
          bool doswap = up ? bFirst : aFirst;
          if (doswap){ sv[i]=vb; sv[p]=va; si[i]=ib; si[p]=ia; }
        }
      }
      __syncthreads();
    }
  }
  for (int t=tid; t<NPROP; t+=1024){
    int idx = imin(si[t], NCLS*HW - 1);
    TOPC[t] = idx / HW;
    TOPS[t] = idx % HW;
  }
}

// ---------------- fused qbuild + attention + LN/FFN/LN + heads + decode (R11-proven) ----------
__global__ __launch_bounds__(256) void k_attn(const float* __restrict__ KK, const float* __restrict__ VV,
                                              const float* __restrict__ LFF,
                                              const int* __restrict__ TOPS, const int* __restrict__ TOPC,
                                              const float* __restrict__ Wcls, const float* __restrict__ bcls,
                                              const float* __restrict__ pW1, const float* __restrict__ pb1,
                                              const float* __restrict__ WP2T, const float* __restrict__ pb2,
                                              const float* __restrict__ WQT, const float* __restrict__ bq,
                                              const float* __restrict__ WOT, const float* __restrict__ bo,
                                              const float* __restrict__ g1, const float* __restrict__ b1,
                                              const float* __restrict__ WF1T, const float* __restrict__ bf1,
                                              const float* __restrict__ WF2T, const float* __restrict__ bf2,
                                              const float* __restrict__ g2, const float* __restrict__ b2,
                                              const float* __restrict__ Wc, const float* __restrict__ bc,
                                              const float* __restrict__ Wh, const float* __restrict__ bh,
                                              const float* __restrict__ Wd, const float* __restrict__ bd,
                                              const float* __restrict__ Wr, const float* __restrict__ br,
                                              const float* __restrict__ Whm2, const float* __restrict__ bhm2,
                                              float* __restrict__ out){
  int n = blockIdx.x, tid = threadIdx.x;
  __shared__ __align__(16) float qhL[128];
  __shared__ float sc[8*441];
  __shared__ int   kiL[441];
  __shared__ __align__(16) float ctxL[128];
  __shared__ float xL[128];
  __shared__ float hidL[256];
  __shared__ float sumsL[8];
  __shared__ float stat[2];
  __shared__ float dots[16];
  int sp = TOPS[n];
  int cls = TOPC[n];
  const int kb64 = (tid>>7)*64, c128 = tid&127;
  float qreg = 0.f;
  if (tid < 128){
    float qx = (float)(sp/132)+0.5f, qy = (float)(sp%132)+0.5f;
    ctxL[tid] = fmaxf(qx*pW1[tid] + qy*pW1[128+tid] + pb1[tid], 0.f);
    qreg = LFF[(size_t)sp*128+tid] + Wcls[tid*6+cls] + bcls[tid];
  }
  __syncthreads();
  {
    const float4* wp = (const float4*)(WP2T + (size_t)c128*128 + kb64);
    float pe = 0.f;
    #pragma unroll
    for (int k4=0;k4<16;++k4){
      float4 w = wp[k4]; int kb = kb64 + k4*4;
      pe += ctxL[kb]*w.x + ctxL[kb+1]*w.y + ctxL[kb+2]*w.z + ctxL[kb+3]*w.w;
    }
    sc[tid] = pe;
  }
  __syncthreads();
  if (tid < 128) xL[tid] = qreg + pb2[tid] + sc[tid] + sc[tid+128];
  __syncthreads();
  {
    const float4* wp = (const float4*)(WQT + (size_t)c128*128 + kb64);
    float qh = 0.f;
    #pragma unroll
    for (int k4=0;k4<16;++k4){
      float4 w = wp[k4]; int kb = kb64 + k4*4;
      qh += xL[kb]*w.x + xL[kb+1]*w.y + xL[kb+2]*w.z + xL[kb+3]*w.w;
    }
    sc[tid] = qh;
  }
  __syncthreads();
  if (tid < 128) qhL[tid] = bq[tid] + sc[tid] + sc[tid+128];
  __syncthreads();
  int spx = sp/192, spy = sp%132;       // faithful to ref's //X_GRID, %Y_GRID
  for (int l = tid; l < 441; l += 256){
    int a = l/21, bb = l%21;
    int kidx = (spx + a - 10)*192 + (spy + bb - 10);
    bool msk = (kidx < 0) || (kidx >= HW);
    int kc = imin(imax(kidx,0), HW-1);
    kiL[l] = kc;
    const float4* kk4 = (const float4*)(KK + (size_t)kc*128);
    const float4* qh4 = (const float4*)qhL;
    #pragma unroll
    for (int hh=0; hh<8; ++hh){
      float acc = 0.f;
      #pragma unroll
      for (int d4=0; d4<4; ++d4){
        float4 kv = kk4[hh*4+d4]; float4 qv = qh4[hh*4+d4];
        acc += kv.x*qv.x + kv.y*qv.y + kv.z*qv.z + kv.w*qv.w;
      }
      sc[hh*441+l] = msk ? -1e9f : acc*0.25f;
    }
  }
  __syncthreads();
  int wave = tid>>6, lane = tid&63;
  for (int hh = wave; hh < 8; hh += 4){
    float mx = -3.0e38f;
    for (int l = lane; l < 441; l += 64) mx = fmaxf(mx, sc[hh*441+l]);
    #pragma unroll
    for (int off=32; off; off>>=1) mx = fmaxf(mx, __shfl_xor(mx, off));
    float sum = 0.f;
    for (int l = lane; l < 441; l += 64){
      float e = __expf(sc[hh*441+l] - mx);
      sc[hh*441+l] = e; sum += e;
    }
    #pragma unroll
    for (int off=32; off; off>>=1) sum += __shfl_xor(sum, off);
    if (lane==0) sumsL[hh] = sum;
  }
  __syncthreads();
  for (int hh = wave; hh < 8; hh += 4){
    float a[16];
    #pragma unroll
    for (int d=0; d<16; ++d) a[d]=0.f;
    for (int l = lane; l < 441; l += 64){
      float w = sc[hh*441+l];
      const float4* vv4 = (const float4*)(VV + (size_t)kiL[l]*128 + hh*16);
      #pragma unroll
      for (int d4=0; d4<4; ++d4){
        float4 v = vv4[d4];
        a[d4*4+0]+=w*v.x; a[d4*4+1]+=w*v.y; a[d4*4+2]+=w*v.z; a[d4*4+3]+=w*v.w;
      }
    }
    #pragma unroll
    for (int d=0; d<16; ++d){
      #pragma unroll
      for (int off=32; off; off>>=1) a[d] += __shfl_xor(a[d], off);
    }
    if (lane==0){
      float inv = 1.f/sumsL[hh];
      #pragma unroll
      for (int d=0; d<16; ++d) ctxL[hh*16+d] = a[d]*inv;
    }
  }
  __syncthreads();
  {
    const float4* wp = (const float4*)(WOT + (size_t)c128*128 + kb64);
    float acc = 0.f;
    #pragma unroll
    for (int k4=0;k4<16;++k4){
      float4 w = wp[k4]; int kb = kb64 + k4*4;
      acc += ctxL[kb]*w.x + ctxL[kb+1]*w.y + ctxL[kb+2]*w.z + ctxL[kb+3]*w.w;
    }
    sc[tid] = acc;
  }
  __syncthreads();
  float x1v = 0.f;
  if (tid < 128){
    x1v = qreg + bo[tid] + sc[tid] + sc[tid+128];
    xL[tid] = x1v;
  }
  __syncthreads();
  if (tid < 64){
    float u0 = xL[tid], u1 = xL[tid+64];
    float s = u0+u1, s2 = u0*u0+u1*u1;
    #pragma unroll
    for (int off=32; off; off>>=1){ s += __shfl_xor(s, off); s2 += __shfl_xor(s2, off); }
    if (tid==0){ float mean = s*(1.f/128.f); float var = s2*(1.f/128.f) - mean*mean;
      stat[0]=mean; stat[1]=rsqrtf(var + 1e-5f); }
  }
  __syncthreads();
  if (tid < 128) xL[tid] = (x1v - stat[0])*stat[1]*g1[tid] + b1[tid];
  __syncthreads();
  {
    const float4* wp = (const float4*)(WF1T + (size_t)tid*128);
    float hv = bf1[tid];
    #pragma unroll 8
    for (int k4=0;k4<32;++k4){
      float4 w = wp[k4]; int kb = k4*4;
      hv += xL[kb]*w.x + xL[kb+1]*w.y + xL[kb+2]*w.z + xL[kb+3]*w.w;
    }
    hidL[tid] = fmaxf(hv, 0.f);
  }
  __syncthreads();
  {
    int kb0 = (tid>>7)*128;
    const float4* wp = (const float4*)(WF2T + (size_t)c128*256 + kb0);
    float acc = 0.f;
    #pragma unroll 8
    for (int k4=0;k4<32;++k4){
      float4 w = wp[k4]; int kb = kb0 + k4*4;
      acc += hidL[kb]*w.x + hidL[kb+1]*w.y + hidL[kb+2]*w.z + hidL[kb+3]*w.w;
    }
    sc[tid] = acc;
  }
  __syncthreads();
  float x2v = 0.f;
  if (tid < 128) x2v = xL[tid] + bf2[tid] + sc[tid] + sc[tid+128];
  __syncthreads();
  if (tid < 128) hidL[tid] = x2v;
  __syncthreads();
  if (tid < 64){
    float u0 = hidL[tid], u1 = hidL[tid+64];
    float s = u0+u1, s2 = u0*u0+u1*u1;
    #pragma unroll
    for (int off=32; off; off>>=1){ s += __shfl_xor(s, off); s2 += __shfl_xor(s2, off); }
    if (tid==0){ float mean = s*(1.f/128.f); float var = s2*(1.f/128.f) - mean*mean;
      stat[0]=mean; stat[1]=rsqrtf(var + 1e-5f); }
  }
  __syncthreads();
  if (tid < 128) xL[tid] = (x2v - stat[0])*stat[1]*g2[tid] + b2[tid];   // final x2
  __syncthreads();
  if (tid < 14){
    const float* Wp; float bb;
    if (tid < 2)      { Wp = Wc + tid*128;        bb = bc[tid];      }
    else if (tid < 3) { Wp = Wh;                  bb = bh[0];        }
    else if (tid < 6) { Wp = Wd + (tid-3)*128;    bb = bd[tid-3];    }
    else if (tid < 8) { Wp = Wr + (tid-6)*128;    bb = br[tid-6];    }
    else              { Wp = Whm2 + (tid-8)*128;  bb = bhm2[tid-8];  }
    float acc = bb;
    for (int k=0;k<128;++k) acc += xL[k]*Wp[k];
    dots[tid] = acc;
  }
  __syncthreads();
  if (tid == 0){
    float qpx = (float)(sp/132)+0.5f, qpy = (float)(sp%132)+0.5f;
    float cx = (dots[0]+qpx)*0.64f - 61.44f;
    float cy = (dots[1]+qpy)*0.64f - 42.24f;
    float e0 = expf(dots[3]), e1 = expf(dots[4]), e2 = expf(dots[5]);
    float hgt = dots[2] - e2*0.5f;
    float rot = atanf(dots[6]/(dots[7] + 1e-6f));
    float bestv = -1.f; int bestc = 0;
    #pragma unroll
    for (int m=0;m<6;++m){
      float s = 1.f/(1.f + expf(-dots[8+m]));
      if (s > bestv){ bestv = s; bestc = m; }
    }
    float* o = out + (size_t)n*9;
    o[0]=cx; o[1]=cy; o[2]=hgt; o[3]=e0; o[4]=e1; o[5]=e2; o[6]=rot;
    o[7]=(float)bestc; o[8]=bestv;
  }
}

// ---------------- launcher ----------------
extern "C" void kernel_launch(void* const* d_in, const int* in_sizes, int n_in,
                              void* d_out, int out_size, void* d_ws, size_t ws_size,
                              hipStream_t stream){
  (void)in_sizes; (void)n_in; (void)out_size;
  const float* IN   = (const float*)d_in[0];
  const float* Wsh  = (const float*)d_in[1];
  const float* bsh  = (const float*)d_in[2];
  const float* Whm  = (const float*)d_in[3];
  const float* bhm  = (const float*)d_in[4];
  const float* Wcls = (const float*)d_in[5];
  const float* bcls = (const float*)d_in[6];
  const float* Wp1  = (const float*)d_in[7];
  const float* bp1  = (const float*)d_in[8];
  const float* Wp2  = (const float*)d_in[9];
  const float* bp2  = (const float*)d_in[10];
  const float* Wq   = (const float*)d_in[11];
  const float* bq   = (const float*)d_in[12];
  const float* Wk   = (const float*)d_in[13];
  const float* bk   = (const float*)d_in[14];
  const float* Wv   = (const float*)d_in[15];
  const float* bv   = (const float*)d_in[16];
  const float* Wo   = (const float*)d_in[17];
  const float* bo   = (const float*)d_in[18];
  const float* g1   = (const float*)d_in[19];
  const float* b1   = (const float*)d_in[20];
  const float* g2   = (const float*)d_in[21];
  const float* b2   = (const float*)d_in[22];
  const float* Wf1  = (const float*)d_in[23];
  const float* bf1  = (const float*)d_in[24];
  const float* Wf2  = (const float*)d_in[25];
  const float* bf2  = (const float*)d_in[26];
  const float* Wc   = (const float*)d_in[27];
  const float* bc   = (const float*)d_in[28];
  const float* Wh   = (const float*)d_in[29];
  const float* bh   = (const float*)d_in[30];
  const float* Wd   = (const float*)d_in[31];
  const float* bd   = (const float*)d_in[32];
  const float* Wr   = (const float*)d_in[33];
  const float* br   = (const float*)d_in[34];
  const float* Whm2 = (const float*)d_in[37];
  const float* bhm2 = (const float*)d_in[38];
  float* out = (float*)d_out;
  float* W = (float*)d_ws;

  const size_t N_LFF  = (size_t)HW*128;
  const size_t OFF_LFF  = 0;
  const size_t OFF_KK   = OFF_LFF + N_LFF;         // conv1 partial P0, then KK
  const size_t OFF_VV   = OFF_KK + N_LFF;          // conv1 partial P1, then VV
  const size_t OFF_W6   = OFF_VV + N_LFF;          // 6912
  const size_t OFF_HMS  = OFF_W6 + 6912;           // 152064
  const size_t OFF_VALS = OFF_HMS + 152064;        // 152064
  const size_t OFF_HIST = OFF_VALS + 152064;       // 65536
  const size_t OFF_SCAN = OFF_HIST + 65536;        // 16
  const size_t OFF_CNT  = OFF_SCAN + 16;           // 16
  const size_t OFF_CV   = OFF_CNT + 16;            // CAP
  const size_t OFF_CI   = OFF_CV + CAP;            // CAP
  const size_t OFF_TOPS = OFF_CI + CAP;            // 512
  const size_t OFF_TOPC = OFF_TOPS + 512;          // 512
  const size_t OFF_WQT  = OFF_TOPC + 512;          // 16384
  const size_t OFF_WP2T = OFF_WQT + 16384;         // 16384
  const size_t OFF_WOT  = OFF_WP2T + 16384;        // 16384
  const size_t OFF_WF1T = OFF_WOT + 16384;         // 32768
  const size_t OFF_WF2T = OFF_WF1T + 32768;        // 32768
  const size_t OFF_BQ0  = OFF_WF2T + 32768;        // 184320 floats (= 368640 bf16)
  const size_t OFF_BQ1  = OFF_BQ0 + 184320;
  const size_t OFF_BQ2  = OFF_BQ1 + 184320;
  const size_t TOTAL    = OFF_BQ2 + 184320;
  if (ws_size < TOTAL*sizeof(float)) return;

  ushort_t* BQ0 = (ushort_t*)(W + OFF_BQ0);
  ushort_t* BQ1 = (ushort_t*)(W + OFF_BQ1);
  ushort_t* BQ2 = (ushort_t*)(W + OFF_BQ2);

  // k_wt also zeroes HIST|SCAN|CNT (65568 ints, contiguous at OFF_HIST)
  k_wt    <<<1152, 256, 0, stream>>>(Wsh, Whm, Wq, Wp2, Wo, Wf1, Wf2,
                                     W+OFF_W6,
                                     W+OFF_WQT, W+OFF_WP2T, W+OFF_WOT, W+OFF_WF1T, W+OFF_WF2T,
                                     BQ0, BQ1, BQ2,
                                     (int*)(W+OFF_HIST));
  k_conv1 <<<dim3(396,2), 256, 0, stream>>>(IN, BQ0, BQ1, BQ2, W+OFF_KK, W+OFF_VV);
  k_cadd2 <<<3168, 256, 0, stream>>>(W+OFF_LFF, W+OFF_KK, W+OFF_VV, bsh);
  k_mid   <<<1188, 256, 0, stream>>>(W+OFF_LFF, Wp1, bp1, Wp2, bp2, Wk, bk, Wv, bv,
                                     W+OFF_KK, W+OFF_VV, W+OFF_W6, bhm, W+OFF_HMS);
  k_nms   <<<594,  256, 0, stream>>>(W+OFF_HMS, W+OFF_VALS, (int*)(W+OFF_HIST));
  k_scan  <<<1,   1024, 0, stream>>>((const int*)(W+OFF_HIST), (int*)(W+OFF_SCAN));
  k_collect<<<594, 256, 0, stream>>>(W+OFF_VALS, (const int*)(W+OFF_SCAN),
                                     (int*)(W+OFF_CNT), W+OFF_CV, (int*)(W+OFF_CI));
  k_sort  <<<1,   1024, 0, stream>>>(W+OFF_CV, (const int*)(W+OFF_CI), (const int*)(W+OFF_CNT),
                                     (int*)(W+OFF_TOPS), (int*)(W+OFF_TOPC));
  k_attn  <<<500,  256, 0, stream>>>(W+OFF_KK, W+OFF_VV, W+OFF_LFF,
                                     (const int*)(W+OFF_TOPS), (const int*)(W+OFF_TOPC),
                                     Wcls, bcls, Wp1, bp1, W+OFF_WP2T, bp2, W+OFF_WQT, bq,
                                     W+OFF_WOT, bo, g1, b1, W+OFF_WF1T, bf1, W+OFF_WF2T, bf2, g2, b2,
                                     Wc, bc, Wh, bh, Wd, bd, Wr, br, Whm2, bhm2, out);
}